// Round 2
// baseline (1363.882 us; speedup 1.0000x reference)
//
#include <hip/hip_runtime.h>
#include <hip/hip_cooperative_groups.h>
#include <math.h>

namespace cg = cooperative_groups;

// Problem constants
#define CC   128         // channels
#define NL   16384       // N * H * W = 4*64*64
#define OMP  112         // padded om row stride (108 real cols)
#define HH   64
#define WW   64

typedef __attribute__((ext_vector_type(8))) short short8;
typedef __attribute__((ext_vector_type(4))) float f32x4;

__device__ __forceinline__ unsigned short f2bf(float f) {
    union { float f; unsigned u; } v; v.f = f;
    unsigned r = v.u + 0x7fff + ((v.u >> 16) & 1);   // RNE
    return (unsigned short)(r >> 16);
}
__device__ __forceinline__ float bf2f(unsigned short u) {
    union { unsigned u; float f; } v; v.u = ((unsigned)u) << 16;
    return v.f;
}

// ---------------------------------------------------------------------------
// Shared-memory layout (one 87 KB block, phase-dependent views):
//   As  @ 0     : u16[64*136]  = 17408 B   (all GEMM phases)
//   Bs  @ 17408 : u16[240*136] = 65280 B   (vom) / u16[128*136] = 34816 (others)
//   Xs  @ 52224 : f32[64*132]  = 33792 B   (final: residual stage + T[128*66])
//   bn0 @ 86016 : f32[128]                  (bnsc / lstat[0:128])
//   bn1 @ 86528 : f32[128]                  (bnsh / lstat[128:256])
// ---------------------------------------------------------------------------
#define SM_AS   0
#define SM_BS   17408
#define SM_XS   52224
#define SM_BN0  86016
#define SM_BN1  86528
#define SMEM_SZ 87040

// ---------------------------------------------------------------------------
// Phase: fused value+om GEMM  [M=16384 x N=240 x K=128]
// Block covers 64 rows x 240 cols. 16 waves: wave w -> row-tile (w>>2),
// col-chunk (w&3) of 4,4,4,3 frags. Same MFMA chain as the 157us baseline.
// ---------------------------------------------------------------------------
template<int MODE>
__device__ __forceinline__ void vom_phase(
    char* smem, int nb,
    const float* __restrict__ Ain, const unsigned short* __restrict__ Wcomb,
    const float* __restrict__ bv, const float* __restrict__ bom,
    const float* __restrict__ stats, const float* __restrict__ gamma,
    const float* __restrict__ beta,
    unsigned short* __restrict__ val, float* __restrict__ omb)
{
    unsigned short* As = (unsigned short*)(smem + SM_AS);
    unsigned short* Bs = (unsigned short*)(smem + SM_BS);
    float* bnsc = (float*)(smem + SM_BN0);
    float* bnsh = (float*)(smem + SM_BN1);
    int tid = threadIdx.x;

    if (MODE == 1 && tid < 128) {
        const float inv = 1.0f / 16384.0f;
        float mean = stats[tid] * inv;
        float var  = stats[128 + tid] * inv - mean * mean;
        float sc   = rsqrtf(var + 1e-5f) * gamma[tid];
        bnsc[tid] = sc;
        bnsh[tid] = beta[tid] - mean * sc;
    }
    // stage B once: 240 rows x 128 bf16 = 3840 chunks of 8
#pragma unroll
    for (int i = 0; i < 4; i++) {
        int id = tid + i * 1024;
        if (id < 3840) {
            int r = id >> 4, kc = id & 15;
            float4 v = *(const float4*)(Wcomb + (size_t)r * CC + kc * 8);
            *(float4*)(&Bs[r * 136 + kc * 8]) = v;
        }
    }

    int w = tid >> 6, l = tid & 63, lr = l & 15, lk = l >> 4;
    int rtl = w >> 2, ccw = w & 3;
    int F = ccw * 4, NF = (ccw == 3) ? 3 : 4;

    for (int vb = blockIdx.x; vb < 256; vb += nb) {
        int block_m = vb * 64;
        __syncthreads();                  // Bs/bn ready; previous readers done
        if (MODE == 0) {
            int n = block_m >> 12, hw0 = block_m & 4095;
#pragma unroll
            for (int i = 0; i < 2; i++) {
                int id = tid + i * 1024;
                int c = id >> 4, j4 = id & 15;
                float4 v = *(const float4*)(Ain + (((size_t)(n * CC + c)) << 12) + hw0 + j4 * 4);
                As[(j4 * 4 + 0) * 136 + c] = f2bf(v.x);
                As[(j4 * 4 + 1) * 136 + c] = f2bf(v.y);
                As[(j4 * 4 + 2) * 136 + c] = f2bf(v.z);
                As[(j4 * 4 + 3) * 136 + c] = f2bf(v.w);
            }
        } else {
#pragma unroll
            for (int i = 0; i < 2; i++) {
                int id = tid + i * 1024;
                int r = id >> 5, c4 = id & 31;
                float4 v = *(const float4*)(Ain + (size_t)(block_m + r) * CC + c4 * 4);
                int c = c4 * 4;
                float a0 = fmaxf(v.x * bnsc[c + 0] + bnsh[c + 0], 0.0f);
                float a1 = fmaxf(v.y * bnsc[c + 1] + bnsh[c + 1], 0.0f);
                float a2 = fmaxf(v.z * bnsc[c + 2] + bnsh[c + 2], 0.0f);
                float a3 = fmaxf(v.w * bnsc[c + 3] + bnsh[c + 3], 0.0f);
                As[r * 136 + c + 0] = f2bf(a0);
                As[r * 136 + c + 1] = f2bf(a1);
                As[r * 136 + c + 2] = f2bf(a2);
                As[r * 136 + c + 3] = f2bf(a3);
            }
        }
        __syncthreads();

        f32x4 acc[4];
#pragma unroll
        for (int f = 0; f < 4; f++) acc[f] = (f32x4){0.f, 0.f, 0.f, 0.f};
#pragma unroll
        for (int kk = 0; kk < 4; kk++) {
            short8 a = *(const short8*)(&As[(rtl * 16 + lr) * 136 + kk * 32 + lk * 8]);
#pragma unroll
            for (int f = 0; f < 4; f++) {
                if (f < NF) {
                    short8 b = *(const short8*)(&Bs[((F + f) * 16 + lr) * 136 + kk * 32 + lk * 8]);
                    acc[f] = __builtin_amdgcn_mfma_f32_16x16x32_bf16(a, b, acc[f], 0, 0, 0);
                }
            }
        }

        int row0 = block_m + rtl * 16 + lk * 4;
#pragma unroll
        for (int f = 0; f < 4; f++) {
            if (f < NF) {
                int frag = F + f;
                if (frag < 8) {              // value output (bf16, +bv)
                    int col = frag * 16 + lr;
                    float bb = bv[col];
#pragma unroll
                    for (int r = 0; r < 4; r++)
                        val[(size_t)(row0 + r) * CC + col] = f2bf(acc[f][r] + bb);
                } else {                     // offset/mask output (fp32, +bom)
                    int ocol = (frag - 8) * 16 + lr;
                    float bb = (ocol < 108) ? bom[ocol] : 0.0f;
#pragma unroll
                    for (int r = 0; r < 4; r++)
                        omb[(size_t)(row0 + r) * OMP + ocol] = acc[f][r] + bb;
                }
            }
        }
    }
}

// ---------------------------------------------------------------------------
// Phase: deformable sampling. 1024 virtual blocks x 1024 threads = 1M lanes,
// 16 lanes per (nl,g) unit, 2 channels/lane. Identical body to baseline.
// ---------------------------------------------------------------------------
__device__ __forceinline__ void sample_phase(
    int nb, const unsigned short* __restrict__ val,
    const float* __restrict__ omb, unsigned int* __restrict__ sbuf)
{
    int tid = threadIdx.x;
    for (int vbk = blockIdx.x; vbk < 1024; vbk += nb) {
        int gid = vbk * 1024 + tid;
        int unit = gid >> 4;
        int lane16 = gid & 15;
        int nl = unit >> 2;
        int g = unit & 3;
        int n = nl >> 12;
        int hw = nl & 4095;
        int h = hw >> 6;
        int w = hw & 63;

        const float* omp_ = omb + (size_t)nl * OMP + g * 27;
        const unsigned short* vp = val + (((size_t)n) << 19) + g * 32 + lane16 * 2;

        float acc0 = 0.0f, acc1 = 0.0f;
#pragma unroll
        for (int k = 0; k < 9; k++) {
            float ox = omp_[2 * k];
            float oy = omp_[2 * k + 1];
            float mk = omp_[18 + k];
            float ly = (float)(h + k / 3 - 1) + oy;
            float lx = (float)(w + k % 3 - 1) + ox;
            float y0f = floorf(ly), x0f = floorf(lx);
            float wy = ly - y0f, wx = lx - x0f;
            int y0 = (int)y0f, x0 = (int)x0f;

            float v0 = 0.0f, v1 = 0.0f;
#pragma unroll
            for (int cy = 0; cy < 2; cy++) {
#pragma unroll
                for (int cx = 0; cx < 2; cx++) {
                    int yi = y0 + cy, xi = x0 + cx;
                    float wgt = (cy ? wy : 1.0f - wy) * (cx ? wx : 1.0f - wx);
                    bool valid = (yi >= 0) && (yi < HH) && (xi >= 0) && (xi < WW);
                    wgt = valid ? wgt : 0.0f;
                    int yc = min(max(yi, 0), HH - 1);
                    int xc = min(max(xi, 0), WW - 1);
                    unsigned int pv = *(const unsigned int*)(vp + (size_t)(yc * WW + xc) * CC);
                    v0 += bf2f((unsigned short)(pv & 0xffff)) * wgt;
                    v1 += bf2f((unsigned short)(pv >> 16)) * wgt;
                }
            }
            acc0 += mk * v0;
            acc1 += mk * v1;
        }
        unsigned int packed = (unsigned int)f2bf(acc0) | ((unsigned int)f2bf(acc1) << 16);
        sbuf[(size_t)nl * 64 + g * 16 + lane16] = packed;
    }
}

// ---------------------------------------------------------------------------
// Phase: Wo GEMM + fused BN-stats. Block = 64 rows x 128 cols, 16 waves
// in a 4x4 grid (16 rows x 32 cols each).
// ---------------------------------------------------------------------------
__device__ __forceinline__ void obn_phase(
    char* smem, int nb,
    const unsigned short* __restrict__ A, const unsigned short* __restrict__ Bt,
    float* __restrict__ ybuf, float* __restrict__ stats)
{
    unsigned short* As = (unsigned short*)(smem + SM_AS);
    unsigned short* Bs = (unsigned short*)(smem + SM_BS);
    float* lstat = (float*)(smem + SM_BN0);   // 256 floats
    int tid = threadIdx.x;

    if (tid < 256) lstat[tid] = 0.0f;
#pragma unroll
    for (int i = 0; i < 2; i++) {
        int id = tid + i * 1024;
        int r = id >> 4, kc = id & 15;
        float4 v = *(const float4*)(Bt + (size_t)r * CC + kc * 8);
        *(float4*)(&Bs[r * 136 + kc * 8]) = v;
    }

    int w = tid >> 6, l = tid & 63, lr = l & 15, lk = l >> 4;
    int wr = w & 3, wc = w >> 2;

    for (int vb = blockIdx.x; vb < 256; vb += nb) {
        int block_m = vb * 64;
        __syncthreads();                      // Bs/lstat ready; prev readers done
        {
            int r = tid >> 4, kc = tid & 15;
            float4 v = *(const float4*)(A + (size_t)(block_m + r) * CC + kc * 8);
            *(float4*)(&As[r * 136 + kc * 8]) = v;
        }
        __syncthreads();

        f32x4 acc[2];
        acc[0] = (f32x4){0.f, 0.f, 0.f, 0.f};
        acc[1] = (f32x4){0.f, 0.f, 0.f, 0.f};
#pragma unroll
        for (int kk = 0; kk < 4; kk++) {
            short8 a = *(const short8*)(&As[(wr * 16 + lr) * 136 + kk * 32 + lk * 8]);
#pragma unroll
            for (int nt = 0; nt < 2; nt++) {
                short8 b = *(const short8*)(&Bs[(wc * 32 + nt * 16 + lr) * 136 + kk * 32 + lk * 8]);
                acc[nt] = __builtin_amdgcn_mfma_f32_16x16x32_bf16(a, b, acc[nt], 0, 0, 0);
            }
        }
        int row0 = block_m + wr * 16 + lk * 4;
#pragma unroll
        for (int nt = 0; nt < 2; nt++) {
            int col = wc * 32 + nt * 16 + lr;
            float s = 0.0f, sq = 0.0f;
#pragma unroll
            for (int r = 0; r < 4; r++) {
                float v = acc[nt][r];
                ybuf[(size_t)(row0 + r) * CC + col] = v;
                s += v;
                sq += v * v;
            }
            atomicAdd(&lstat[col], s);
            atomicAdd(&lstat[128 + col], sq);
        }
    }
    __syncthreads();
    if (tid < 128) {
        atomicAdd(&stats[tid], lstat[tid]);
        atomicAdd(&stats[128 + tid], lstat[128 + tid]);
    }
}

// ---------------------------------------------------------------------------
// Phase: final GEMM  A = bn(ybuf) + x_residual(NCHW), B = Wc; out NCHW fp32.
// Block = 64 rows x 128 cols, 16 waves 4x4. Transpose epilogue via T=Xs slot.
// ---------------------------------------------------------------------------
__device__ __forceinline__ void final_phase(
    char* smem, int nb,
    const float* __restrict__ ybuf, const float* __restrict__ x,
    const unsigned short* __restrict__ Bt, const float* __restrict__ stats,
    const float* __restrict__ gamma, const float* __restrict__ beta,
    float* __restrict__ out)
{
    unsigned short* As = (unsigned short*)(smem + SM_AS);
    unsigned short* Bs = (unsigned short*)(smem + SM_BS);
    float* Xs = (float*)(smem + SM_XS);       // [64][132] stage, then T[128][66]
    float* bnsc = (float*)(smem + SM_BN0);
    float* bnsh = (float*)(smem + SM_BN1);
    int tid = threadIdx.x;

    if (tid < 128) {
        const float inv = 1.0f / 16384.0f;
        float mean = stats[tid] * inv;
        float var  = stats[128 + tid] * inv - mean * mean;
        float sc   = rsqrtf(var + 1e-5f) * gamma[tid];
        bnsc[tid] = sc;
        bnsh[tid] = beta[tid] - mean * sc;
    }
#pragma unroll
    for (int i = 0; i < 2; i++) {
        int id = tid + i * 1024;
        int r = id >> 4, kc = id & 15;
        float4 v = *(const float4*)(Bt + (size_t)r * CC + kc * 8);
        *(float4*)(&Bs[r * 136 + kc * 8]) = v;
    }

    int w = tid >> 6, l = tid & 63, lr = l & 15, lk = l >> 4;
    int wr = w & 3, wc = w >> 2;

    for (int vb = blockIdx.x; vb < 256; vb += nb) {
        int block_m = vb * 64;
        int n = block_m >> 12, hw0 = block_m & 4095;
        __syncthreads();                      // Bs/bn ready; prev T reads done
        // stage x residual (NCHW -> LDS transpose, fp32)
#pragma unroll
        for (int i = 0; i < 2; i++) {
            int id = tid + i * 1024;
            int c = id >> 4, j4 = id & 15;
            float4 v = *(const float4*)(x + (((size_t)(n * CC + c)) << 12) + hw0 + j4 * 4);
            Xs[(j4 * 4 + 0) * 132 + c] = v.x;
            Xs[(j4 * 4 + 1) * 132 + c] = v.y;
            Xs[(j4 * 4 + 2) * 132 + c] = v.z;
            Xs[(j4 * 4 + 3) * 132 + c] = v.w;
        }
        __syncthreads();
        // stage A = bn(ybuf) + Xs
#pragma unroll
        for (int i = 0; i < 2; i++) {
            int id = tid + i * 1024;
            int r = id >> 5, c4 = id & 31;
            float4 v = *(const float4*)(ybuf + (size_t)(block_m + r) * CC + c4 * 4);
            int c = c4 * 4;
            float a0 = v.x * bnsc[c + 0] + bnsh[c + 0] + Xs[r * 132 + c + 0];
            float a1 = v.y * bnsc[c + 1] + bnsh[c + 1] + Xs[r * 132 + c + 1];
            float a2 = v.z * bnsc[c + 2] + bnsh[c + 2] + Xs[r * 132 + c + 2];
            float a3 = v.w * bnsc[c + 3] + bnsh[c + 3] + Xs[r * 132 + c + 3];
            As[r * 136 + c + 0] = f2bf(a0);
            As[r * 136 + c + 1] = f2bf(a1);
            As[r * 136 + c + 2] = f2bf(a2);
            As[r * 136 + c + 3] = f2bf(a3);
        }
        __syncthreads();

        f32x4 acc[2];
        acc[0] = (f32x4){0.f, 0.f, 0.f, 0.f};
        acc[1] = (f32x4){0.f, 0.f, 0.f, 0.f};
#pragma unroll
        for (int kk = 0; kk < 4; kk++) {
            short8 a = *(const short8*)(&As[(wr * 16 + lr) * 136 + kk * 32 + lk * 8]);
#pragma unroll
            for (int nt = 0; nt < 2; nt++) {
                short8 b = *(const short8*)(&Bs[(wc * 32 + nt * 16 + lr) * 136 + kk * 32 + lk * 8]);
                acc[nt] = __builtin_amdgcn_mfma_f32_16x16x32_bf16(a, b, acc[nt], 0, 0, 0);
            }
        }

        // NCHW scatter via LDS transpose in the (now dead) Xs slot, stride 66
        float* T = Xs;
        int rloc = wr * 16 + lk * 4;
#pragma unroll
        for (int nt = 0; nt < 2; nt++) {
            int col = wc * 32 + nt * 16 + lr;
#pragma unroll
            for (int r = 0; r < 4; r++)
                T[col * 66 + rloc + r] = acc[nt][r];
        }
        __syncthreads();
        int o = tid >> 3, q = tid & 7;
        float* op = out + (((size_t)(n * CC + o)) << 12) + hw0 + q * 8;
        *(float4*)(op)     = *(const float4*)(&T[o * 66 + q * 8]);
        *(float4*)(op + 4) = *(const float4*)(&T[o * 66 + q * 8 + 4]);
    }
}

// ---------------------------------------------------------------------------
// Mega-kernel: all 8 stages, 7 grid syncs. 256 blocks x 1024 threads,
// 1 block/CU (87 KB LDS), 4 waves/SIMD.
// ---------------------------------------------------------------------------
__global__ __launch_bounds__(1024) void mega_kernel(
    const float* __restrict__ x,
    const float* __restrict__ Wv, const float* __restrict__ bv,
    const float* __restrict__ Wom, const float* __restrict__ bom,
    const float* __restrict__ Wo, const float* __restrict__ gamma,
    const float* __restrict__ beta, const float* __restrict__ Wc,
    unsigned short* Wcomb, unsigned short* WoT, unsigned short* Wcb,
    unsigned short* val, float* omb, unsigned int* sbuf, float* ybuf,
    float* stats, float* out)
{
    __shared__ alignas(16) char smem[SMEM_SZ];
    cg::grid_group grid = cg::this_grid();
    int tid = threadIdx.x;
    int nb = gridDim.x;

    // ---- P0: weight prep + stats zero ----
    for (int b = blockIdx.x; b < 62; b += nb) {
        int i = b * 1024 + tid;              // 63488 = 62*1024 exact
        if (i < 16384) {
            int nn = i >> 7, k = i & 127;
            Wcomb[i] = f2bf(Wv[k * CC + nn]);
        } else if (i < 30720) {
            int j = i - 16384; int nn = j >> 7, k = j & 127;
            Wcomb[16384 + j] = (nn < 108) ? f2bf(Wom[k * 108 + nn]) : (unsigned short)0;
        } else if (i < 47104) {
            int j = i - 30720; int nn = j >> 7, k = j & 127;
            WoT[j] = f2bf(Wo[k * CC + nn]);
        } else {
            int j = i - 47104;
            Wcb[j] = f2bf(Wc[j]);
        }
    }
    if (blockIdx.x == 0 && tid < 512) stats[tid] = 0.0f;

    __threadfence(); grid.sync(); __threadfence();
    // ---- DCN block 1 ----
    vom_phase<0>(smem, nb, x, Wcomb, bv, bom, nullptr, nullptr, nullptr, val, omb);
    __threadfence(); grid.sync(); __threadfence();
    sample_phase(nb, val, omb, sbuf);
    __threadfence(); grid.sync(); __threadfence();
    obn_phase(smem, nb, (const unsigned short*)sbuf, WoT, ybuf, stats);
    __threadfence(); grid.sync(); __threadfence();
    // ---- DCN block 2 ----
    vom_phase<1>(smem, nb, ybuf, Wcomb, bv, bom, stats, gamma, beta, val, omb);
    __threadfence(); grid.sync(); __threadfence();
    sample_phase(nb, val, omb, sbuf);
    __threadfence(); grid.sync(); __threadfence();
    obn_phase(smem, nb, (const unsigned short*)sbuf, WoT, ybuf, stats + 256);
    __threadfence(); grid.sync(); __threadfence();
    // ---- final: bn2 + residual + 1x1 conv ----
    final_phase(smem, nb, ybuf, x, Wcb, stats + 256, gamma, beta, out);
}

// ---------------------------------------------------------------------------
extern "C" void kernel_launch(void* const* d_in, const int* in_sizes, int n_in,
                              void* d_out, int out_size, void* d_ws, size_t ws_size,
                              hipStream_t stream)
{
    const float* x     = (const float*)d_in[0];
    const float* Wv    = (const float*)d_in[1];
    const float* bv    = (const float*)d_in[2];
    const float* Wom   = (const float*)d_in[3];
    const float* bom   = (const float*)d_in[4];
    const float* Wo    = (const float*)d_in[5];
    const float* gamma = (const float*)d_in[6];
    const float* beta  = (const float*)d_in[7];
    const float* Wc    = (const float*)d_in[8];
    float* out = (float*)d_out;

    char* ws = (char*)d_ws;
    unsigned short* val   = (unsigned short*)ws;   ws += (size_t)NL * CC * 2;    // 4 MB
    float*          omb   = (float*)ws;            ws += (size_t)NL * OMP * 4;   // 7.34 MB
    unsigned int*   sbuf  = (unsigned int*)ws;     ws += (size_t)NL * CC * 2;    // 4 MB
    float*          ybuf  = (float*)ws;            ws += (size_t)NL * CC * 4;    // 8 MB
    unsigned short* Wcomb = (unsigned short*)ws;   ws += 240 * 128 * 2;
    unsigned short* WoT   = (unsigned short*)ws;   ws += 128 * 128 * 2;
    unsigned short* Wcb   = (unsigned short*)ws;   ws += 128 * 128 * 2;
    float*          stats = (float*)ws;            ws += 2048;

    int occ = 0;
    if (hipOccupancyMaxActiveBlocksPerMultiprocessor(&occ, (const void*)mega_kernel, 1024, 0)
            != hipSuccess || occ < 1)
        occ = 1;
    int grid = occ * 256;
    if (grid > 256) grid = 256;

    void* args[18];
    args[0]  = (void*)&x;     args[1]  = (void*)&Wv;    args[2]  = (void*)&bv;
    args[3]  = (void*)&Wom;   args[4]  = (void*)&bom;   args[5]  = (void*)&Wo;
    args[6]  = (void*)&gamma; args[7]  = (void*)&beta;  args[8]  = (void*)&Wc;
    args[9]  = (void*)&Wcomb; args[10] = (void*)&WoT;   args[11] = (void*)&Wcb;
    args[12] = (void*)&val;   args[13] = (void*)&omb;   args[14] = (void*)&sbuf;
    args[15] = (void*)&ybuf;  args[16] = (void*)&stats; args[17] = (void*)&out;

    hipLaunchCooperativeKernel((const void*)mega_kernel, dim3(grid), dim3(1024),
                               args, 0, stream);
}

// Round 3
// 173.093 us; speedup vs baseline: 7.8795x; 7.8795x over previous
//
#include <hip/hip_runtime.h>
#include <math.h>

// Problem constants
#define CC   128         // channels
#define NL   16384       // N * H * W = 4*64*64
#define OMP  112         // padded om row stride (108 real cols)
#define HH   64
#define WW   64

typedef __attribute__((ext_vector_type(8))) short short8;
typedef __attribute__((ext_vector_type(4))) float f32x4;

__device__ __forceinline__ unsigned short f2bf(float f) {
    union { float f; unsigned u; } v; v.f = f;
    unsigned r = v.u + 0x7fff + ((v.u >> 16) & 1);   // RNE
    return (unsigned short)(r >> 16);
}
__device__ __forceinline__ float bf2f(unsigned short u) {
    union { unsigned u; float f; } v; v.u = ((unsigned)u) << 16;
    return v.f;
}

// ---------------------------------------------------------------------------
// Fused value+om GEMM: [M=16384 x N=240 x K=128], 256 blocks x 256 thr.
// B (Wv^T | Wom^T, pad to 112) converted fp32->bf16 inline into LDS
// (weights are L2/L3-resident; kills the separate prep dispatch).
// IN_MODE 0: A = x NCHW (LDS transpose staging); also zeros stats (block 0).
// IN_MODE 1: A = bn_relu(ybuf) NHWC, bn applied during staging.
// 4 waves; wave w computes rows w*16..w*16+15 x all 240 cols (15 frags).
// Same MFMA chain as the 157us-verified baseline.
// ---------------------------------------------------------------------------
template<int IN_MODE>
__global__ __launch_bounds__(256) void gemm_vom_kernel(
    const float* __restrict__ Ain, const float* __restrict__ Wv,
    const float* __restrict__ Wom,
    const float* __restrict__ bv, const float* __restrict__ bom,
    const float* __restrict__ stats_in, const float* __restrict__ gamma,
    const float* __restrict__ beta, float* __restrict__ stats_zero,
    unsigned short* __restrict__ val, float* __restrict__ omb)
{
    __shared__ alignas(16) unsigned short As[64 * 136];
    __shared__ alignas(16) unsigned short Bs[240 * 136];
    __shared__ float bnsc[128], bnsh[128];

    int tid = threadIdx.x;
    int block_m = blockIdx.x * 64;

    if (IN_MODE == 0) {
        if (blockIdx.x == 0) {               // zero 512 stats floats for both BNs
            stats_zero[tid] = 0.0f;
            stats_zero[256 + tid] = 0.0f;
        }
    } else {
        if (tid < 128) {
            const float inv = 1.0f / 16384.0f;
            float mean = stats_in[tid] * inv;
            float var  = stats_in[128 + tid] * inv - mean * mean;
            float sc   = rsqrtf(var + 1e-5f) * gamma[tid];
            bnsc[tid] = sc;
            bnsh[tid] = beta[tid] - mean * sc;
        }
    }

    // stage B rows 0..127 = Wv^T (fp32 -> bf16, transpose in LDS)
#pragma unroll
    for (int i = 0; i < 16; i++) {
        int id = tid + i * 256;              // 0..4095
        int k = id & 127, n4 = id >> 7;      // n4 0..31
        float4 v = *(const float4*)(Wv + (size_t)k * CC + n4 * 4);
        int nb0 = n4 * 4;
        Bs[(nb0 + 0) * 136 + k] = f2bf(v.x);
        Bs[(nb0 + 1) * 136 + k] = f2bf(v.y);
        Bs[(nb0 + 2) * 136 + k] = f2bf(v.z);
        Bs[(nb0 + 3) * 136 + k] = f2bf(v.w);
    }
    // stage B rows 128..239 = Wom^T (108 real cols, pad 4 zero rows)
#pragma unroll
    for (int i = 0; i < 14; i++) {
        int id = tid + i * 256;              // 0..3583
        int k = id & 127, n4 = id >> 7;      // n4 0..27
        if (n4 < 27) {
            float4 v = *(const float4*)(Wom + (size_t)k * 108 + n4 * 4);
            int nb0 = 128 + n4 * 4;
            Bs[(nb0 + 0) * 136 + k] = f2bf(v.x);
            Bs[(nb0 + 1) * 136 + k] = f2bf(v.y);
            Bs[(nb0 + 2) * 136 + k] = f2bf(v.z);
            Bs[(nb0 + 3) * 136 + k] = f2bf(v.w);
        } else {
            Bs[236 * 136 + k] = 0; Bs[237 * 136 + k] = 0;
            Bs[238 * 136 + k] = 0; Bs[239 * 136 + k] = 0;
        }
    }

    if (IN_MODE == 0) {
        // A from x NCHW: 128 channels x 16 float4 along hw
        int n   = block_m >> 12;
        int hw0 = block_m & 4095;
#pragma unroll
        for (int i = 0; i < 8; i++) {
            int id = tid + i * 256;          // 0..2047
            int c  = id >> 4, j4 = id & 15;
            float4 v = *(const float4*)(Ain + (((size_t)(n * CC + c)) << 12) + hw0 + j4 * 4);
            As[(j4 * 4 + 0) * 136 + c] = f2bf(v.x);
            As[(j4 * 4 + 1) * 136 + c] = f2bf(v.y);
            As[(j4 * 4 + 2) * 136 + c] = f2bf(v.z);
            As[(j4 * 4 + 3) * 136 + c] = f2bf(v.w);
        }
    } else {
        __syncthreads();                     // bnsc/bnsh ready
#pragma unroll
        for (int i = 0; i < 8; i++) {
            int id = tid + i * 256;          // 0..2047
            int r  = id >> 5, c4 = id & 31;
            float4 v = *(const float4*)(Ain + (size_t)(block_m + r) * CC + c4 * 4);
            int c = c4 * 4;
            float a0 = fmaxf(v.x * bnsc[c + 0] + bnsh[c + 0], 0.0f);
            float a1 = fmaxf(v.y * bnsc[c + 1] + bnsh[c + 1], 0.0f);
            float a2 = fmaxf(v.z * bnsc[c + 2] + bnsh[c + 2], 0.0f);
            float a3 = fmaxf(v.w * bnsc[c + 3] + bnsh[c + 3], 0.0f);
            As[r * 136 + c + 0] = f2bf(a0);
            As[r * 136 + c + 1] = f2bf(a1);
            As[r * 136 + c + 2] = f2bf(a2);
            As[r * 136 + c + 3] = f2bf(a3);
        }
    }
    __syncthreads();

    int w  = tid >> 6;
    int l  = tid & 63;
    int lr = l & 15, lk = l >> 4;

    f32x4 acc[15];
#pragma unroll
    for (int nt = 0; nt < 15; nt++) acc[nt] = (f32x4){0.f, 0.f, 0.f, 0.f};

#pragma unroll
    for (int kk = 0; kk < 4; kk++) {
        short8 a = *(const short8*)(&As[(w * 16 + lr) * 136 + kk * 32 + lk * 8]);
#pragma unroll
        for (int nt = 0; nt < 15; nt++) {
            short8 b = *(const short8*)(&Bs[(nt * 16 + lr) * 136 + kk * 32 + lk * 8]);
            acc[nt] = __builtin_amdgcn_mfma_f32_16x16x32_bf16(a, b, acc[nt], 0, 0, 0);
        }
    }

    int row0 = block_m + w * 16 + lk * 4;
#pragma unroll
    for (int nt = 0; nt < 8; nt++) {
        int col = nt * 16 + lr;
        float bb = bv[col];
#pragma unroll
        for (int r = 0; r < 4; r++)
            val[(size_t)(row0 + r) * CC + col] = f2bf(acc[nt][r] + bb);
    }
#pragma unroll
    for (int nt = 8; nt < 15; nt++) {
        int col = (nt - 8) * 16 + lr;        // 0..111
        float bb = (col < 108) ? bom[col] : 0.0f;
#pragma unroll
        for (int r = 0; r < 4; r++)
            omb[(size_t)(row0 + r) * OMP + col] = acc[nt][r] + bb;
    }
}

// ---------------------------------------------------------------------------
// FUSED deformable sampling + Wo GEMM + BN stats.
// sample->GEMM is row-local: sampled row nl is exactly GEMM A row nl, so the
// sbuf global round-trip is eliminated (sampled values go straight to LDS).
// 512 blocks x 512 threads, 32 rows/block, 2 blocks/CU (44.5 KB LDS).
// Sample: 32 rows x 4 g x 16 lane16 = 2048 tasks, 4/thread (identical math
// to the verified sample_kernel). GEMM: 8 waves in 2x4 grid, 16r x 32c each.
// ---------------------------------------------------------------------------
__global__ __launch_bounds__(512, 4) void samp_obn_kernel(
    const unsigned short* __restrict__ val, const float* __restrict__ omb,
    const float* __restrict__ Wo,
    float* __restrict__ ybuf, float* __restrict__ stats)
{
    __shared__ alignas(16) unsigned short As[32 * 136];
    __shared__ alignas(16) unsigned short Bs[128 * 136];
    __shared__ float lstat[256];

    int tid = threadIdx.x;
    int block_m = blockIdx.x * 32;
    if (tid < 256) lstat[tid] = 0.0f;

    // stage B = Wo^T bf16 (fp32 -> bf16 inline, transpose in LDS)
#pragma unroll
    for (int i = 0; i < 8; i++) {
        int id = tid + i * 512;              // 0..4095
        int k = id & 127, n4 = id >> 7;      // n4 0..31
        float4 v = *(const float4*)(Wo + (size_t)k * CC + n4 * 4);
        int nb0 = n4 * 4;
        Bs[(nb0 + 0) * 136 + k] = f2bf(v.x);
        Bs[(nb0 + 1) * 136 + k] = f2bf(v.y);
        Bs[(nb0 + 2) * 136 + k] = f2bf(v.z);
        Bs[(nb0 + 3) * 136 + k] = f2bf(v.w);
    }

    // sample phase: results written straight into GEMM A tile (bf16 pairs)
    for (int i = 0; i < 4; i++) {
        int t = tid + i * 512;               // 0..2047
        int lane16 = t & 15;
        int ul = t >> 4;                     // 0..127
        int g  = ul & 3;
        int rl = ul >> 2;                    // 0..31
        int nl = block_m + rl;
        int n  = nl >> 12;
        int hw = nl & 4095;
        int h  = hw >> 6;
        int w  = hw & 63;

        const float* omp_ = omb + (size_t)nl * OMP + g * 27;
        const unsigned short* vp = val + (((size_t)n) << 19) + g * 32 + lane16 * 2;

        float acc0 = 0.0f, acc1 = 0.0f;
#pragma unroll
        for (int k = 0; k < 9; k++) {
            float ox = omp_[2 * k];
            float oy = omp_[2 * k + 1];
            float mk = omp_[18 + k];
            float ly = (float)(h + k / 3 - 1) + oy;
            float lx = (float)(w + k % 3 - 1) + ox;
            float y0f = floorf(ly), x0f = floorf(lx);
            float wy = ly - y0f, wx = lx - x0f;
            int y0 = (int)y0f, x0 = (int)x0f;

            float v0 = 0.0f, v1 = 0.0f;
#pragma unroll
            for (int cy = 0; cy < 2; cy++) {
#pragma unroll
                for (int cx = 0; cx < 2; cx++) {
                    int yi = y0 + cy, xi = x0 + cx;
                    float wgt = (cy ? wy : 1.0f - wy) * (cx ? wx : 1.0f - wx);
                    bool valid = (yi >= 0) && (yi < HH) && (xi >= 0) && (xi < WW);
                    wgt = valid ? wgt : 0.0f;
                    int yc = min(max(yi, 0), HH - 1);
                    int xc = min(max(xi, 0), WW - 1);
                    unsigned int pv = *(const unsigned int*)(vp + (size_t)(yc * WW + xc) * CC);
                    v0 += bf2f((unsigned short)(pv & 0xffff)) * wgt;
                    v1 += bf2f((unsigned short)(pv >> 16)) * wgt;
                }
            }
            acc0 += mk * v0;
            acc1 += mk * v1;
        }
        *(unsigned int*)(&As[rl * 136 + g * 32 + lane16 * 2]) =
            (unsigned int)f2bf(acc0) | ((unsigned int)f2bf(acc1) << 16);
    }
    __syncthreads();

    // Wo GEMM: 8 waves, 2 row-tiles x 4 col-chunks
    int w8 = tid >> 6;
    int l  = tid & 63;
    int lr = l & 15, lk = l >> 4;
    int wr = w8 & 1, wc = w8 >> 1;

    f32x4 acc[2];
    acc[0] = (f32x4){0.f, 0.f, 0.f, 0.f};
    acc[1] = (f32x4){0.f, 0.f, 0.f, 0.f};
#pragma unroll
    for (int kk = 0; kk < 4; kk++) {
        short8 a = *(const short8*)(&As[(wr * 16 + lr) * 136 + kk * 32 + lk * 8]);
#pragma unroll
        for (int nt = 0; nt < 2; nt++) {
            short8 b = *(const short8*)(&Bs[(wc * 32 + nt * 16 + lr) * 136 + kk * 32 + lk * 8]);
            acc[nt] = __builtin_amdgcn_mfma_f32_16x16x32_bf16(a, b, acc[nt], 0, 0, 0);
        }
    }

    int row0 = block_m + wr * 16 + lk * 4;
#pragma unroll
    for (int nt = 0; nt < 2; nt++) {
        int col = wc * 32 + nt * 16 + lr;
        float s = 0.0f, sq = 0.0f;
#pragma unroll
        for (int r = 0; r < 4; r++) {
            float v = acc[nt][r];
            ybuf[(size_t)(row0 + r) * CC + col] = v;
            s += v;
            sq += v * v;
        }
        atomicAdd(&lstat[col], s);
        atomicAdd(&lstat[128 + col], sq);
    }
    __syncthreads();
    if (tid < 128) {
        atomicAdd(&stats[tid], lstat[tid]);
        atomicAdd(&stats[128 + tid], lstat[128 + tid]);
    }
}

// ---------------------------------------------------------------------------
// Final GEMM: A = bn(ybuf) + x_residual(NCHW), B = Wc (inline converted);
// out NCHW fp32. 256 blocks x 256 thr, identical compute to baseline.
// ---------------------------------------------------------------------------
__global__ __launch_bounds__(256) void gemm_final_kernel(
    const float* __restrict__ ybuf, const float* __restrict__ x,
    const float* __restrict__ Wc, const float* __restrict__ stats,
    const float* __restrict__ gamma, const float* __restrict__ beta,
    float* __restrict__ out)
{
    __shared__ alignas(16) unsigned short As[64 * 136];
    __shared__ alignas(16) unsigned short Bs[128 * 136];
    __shared__ alignas(16) float Xs[64 * 132];
    __shared__ float bnsc[128], bnsh[128];

    int tid = threadIdx.x;
    int block_m = blockIdx.x * 64;
    int n   = block_m >> 12;
    int hw0 = block_m & 4095;

    if (tid < 128) {
        const float inv = 1.0f / 16384.0f;
        float mean = stats[tid] * inv;
        float var  = stats[128 + tid] * inv - mean * mean;
        float sc   = rsqrtf(var + 1e-5f) * gamma[tid];
        bnsc[tid] = sc;
        bnsh[tid] = beta[tid] - mean * sc;
    }

    // stage x residual (NCHW -> LDS transpose, fp32)
#pragma unroll
    for (int i = 0; i < 8; i++) {
        int id = tid + i * 256;
        int c  = id >> 4, j4 = id & 15;
        float4 v = *(const float4*)(x + (((size_t)(n * CC + c)) << 12) + hw0 + j4 * 4);
        Xs[(j4 * 4 + 0) * 132 + c] = v.x;
        Xs[(j4 * 4 + 1) * 132 + c] = v.y;
        Xs[(j4 * 4 + 2) * 132 + c] = v.z;
        Xs[(j4 * 4 + 3) * 132 + c] = v.w;
    }
    // stage B = Wc (fp32 -> bf16 inline, no transpose: Bt[o][c] = Wc[o][c])
#pragma unroll
    for (int i = 0; i < 16; i++) {
        int id = tid + i * 256;              // 0..4095 float4 tasks
        int r = id >> 5, c4 = id & 31;
        float4 v = *(const float4*)(Wc + (size_t)r * CC + c4 * 4);
        unsigned short* p = &Bs[r * 136 + c4 * 4];
        p[0] = f2bf(v.x); p[1] = f2bf(v.y);
        p[2] = f2bf(v.z); p[3] = f2bf(v.w);
    }
    __syncthreads();

    // stage A = bn(ybuf) + Xs
#pragma unroll
    for (int i = 0; i < 8; i++) {
        int id = tid + i * 256;
        int r  = id >> 5, c4 = id & 31;
        float4 v = *(const float4*)(ybuf + (size_t)(block_m + r) * CC + c4 * 4);
        int c = c4 * 4;
        float a0 = v.x * bnsc[c + 0] + bnsh[c + 0] + Xs[r * 132 + c + 0];
        float a1 = v.y * bnsc[c + 1] + bnsh[c + 1] + Xs[r * 132 + c + 1];
        float a2 = v.z * bnsc[c + 2] + bnsh[c + 2] + Xs[r * 132 + c + 2];
        float a3 = v.w * bnsc[c + 3] + bnsh[c + 3] + Xs[r * 132 + c + 3];
        As[r * 136 + c + 0] = f2bf(a0);
        As[r * 136 + c + 1] = f2bf(a1);
        As[r * 136 + c + 2] = f2bf(a2);
        As[r * 136 + c + 3] = f2bf(a3);
    }
    __syncthreads();

    int w  = tid >> 6;
    int l  = tid & 63;
    int wm = w & 1, wn = w >> 1;
    int lr = l & 15, lk = l >> 4;

    f32x4 acc[2][4];
#pragma unroll
    for (int mt = 0; mt < 2; mt++)
#pragma unroll
        for (int nt = 0; nt < 4; nt++) acc[mt][nt] = (f32x4){0.f, 0.f, 0.f, 0.f};

#pragma unroll
    for (int kk = 0; kk < 4; kk++) {
        short8 a[2], b[4];
#pragma unroll
        for (int mt = 0; mt < 2; mt++)
            a[mt] = *(const short8*)(&As[(wm * 32 + mt * 16 + lr) * 136 + kk * 32 + lk * 8]);
#pragma unroll
        for (int nt = 0; nt < 4; nt++)
            b[nt] = *(const short8*)(&Bs[(wn * 64 + nt * 16 + lr) * 136 + kk * 32 + lk * 8]);
#pragma unroll
        for (int mt = 0; mt < 2; mt++)
#pragma unroll
            for (int nt = 0; nt < 4; nt++)
                acc[mt][nt] = __builtin_amdgcn_mfma_f32_16x16x32_bf16(
                    a[mt], b[nt], acc[mt][nt], 0, 0, 0);
    }

    // NCHW scatter via LDS transpose (reuse Bs as float[128][68])
    __syncthreads();
    float* T = (float*)Bs;
#pragma unroll
    for (int mt = 0; mt < 2; mt++) {
        int rloc = wm * 32 + mt * 16 + lk * 4;
#pragma unroll
        for (int nt = 0; nt < 4; nt++) {
            int col = wn * 64 + nt * 16 + lr;
#pragma unroll
            for (int r = 0; r < 4; r++)
                T[col * 68 + rloc + r] = acc[mt][nt][r];
        }
    }
    __syncthreads();
    int o = tid >> 1, half = tid & 1;
    float* op = out + (((size_t)(n * CC + o)) << 12) + hw0 + half * 32;
#pragma unroll
    for (int i = 0; i < 8; i++) {
        float4 v = *(const float4*)(&T[o * 68 + half * 32 + i * 4]);
        *(float4*)(op + i * 4) = v;
    }
}

// ---------------------------------------------------------------------------
extern "C" void kernel_launch(void* const* d_in, const int* in_sizes, int n_in,
                              void* d_out, int out_size, void* d_ws, size_t ws_size,
                              hipStream_t stream)
{
    const float* x     = (const float*)d_in[0];
    const float* Wv    = (const float*)d_in[1];
    const float* bv    = (const float*)d_in[2];
    const float* Wom   = (const float*)d_in[3];
    const float* bom   = (const float*)d_in[4];
    const float* Wo    = (const float*)d_in[5];
    const float* gamma = (const float*)d_in[6];
    const float* beta  = (const float*)d_in[7];
    const float* Wc    = (const float*)d_in[8];
    float* out = (float*)d_out;

    char* ws = (char*)d_ws;
    unsigned short* val   = (unsigned short*)ws;   ws += (size_t)NL * CC * 2;    // 4 MB
    float*          omb   = (float*)ws;            ws += (size_t)NL * OMP * 4;   // 7.34 MB
    float*          ybuf  = (float*)ws;            ws += (size_t)NL * CC * 4;    // 8 MB
    float*          stats = (float*)ws;            ws += 2048;

    dim3 b256(256), b512(512);

    // ---- DCN block 1 ----
    gemm_vom_kernel<0><<<256, b256, 0, stream>>>(x, Wv, Wom, bv, bom,
                                                 nullptr, nullptr, nullptr,
                                                 stats, val, omb);
    samp_obn_kernel<<<512, b512, 0, stream>>>(val, omb, Wo, ybuf, stats);

    // ---- DCN block 2 (bn+relu fused into A-staging) ----
    gemm_vom_kernel<1><<<256, b256, 0, stream>>>(ybuf, Wv, Wom, bv, bom,
                                                 stats, gamma, beta,
                                                 nullptr, val, omb);
    samp_obn_kernel<<<512, b512, 0, stream>>>(val, omb, Wo, ybuf, stats + 256);

    // ---- final: bn2 + residual + 1x1 conv, NCHW out ----
    gemm_final_kernel<<<256, b256, 0, stream>>>(ybuf, x, Wc, stats + 256, gamma, beta, out);
}

// Round 4
// 172.981 us; speedup vs baseline: 7.8846x; 1.0007x over previous
//
#include <hip/hip_runtime.h>
#include <math.h>

// Problem constants
#define CC   128         // channels
#define NL   16384       // N * H * W = 4*64*64
#define LHW  4096        // H*W
#define OMP  112         // padded om row stride (108 real cols)
#define HH   64
#define WW   64

typedef __attribute__((ext_vector_type(8))) short short8;
typedef __attribute__((ext_vector_type(4))) float f32x4;

__device__ __forceinline__ unsigned short f2bf(float f) {
    union { float f; unsigned u; } v; v.f = f;
    unsigned r = v.u + 0x7fff + ((v.u >> 16) & 1);   // RNE
    return (unsigned short)(r >> 16);
}
__device__ __forceinline__ float bf2f(unsigned short u) {
    union { unsigned u; float f; } v; v.u = ((unsigned)u) << 16;
    return v.f;
}

// ---------------------------------------------------------------------------
// Weight prep + stats zero (identical to the 157us-verified baseline).
// Wcomb[240][128] bf16: rows 0..127 = Wv^T, rows 128..239 = Wom^T (pad->112)
// WoT[128][128] = Wo^T ; Wcb[128][128] = Wc.
// ---------------------------------------------------------------------------
__global__ __launch_bounds__(256) void prep_kernel(
    const float* __restrict__ Wv, const float* __restrict__ Wom,
    const float* __restrict__ Wo, const float* __restrict__ Wc,
    unsigned short* __restrict__ Wcomb, unsigned short* __restrict__ WoT,
    unsigned short* __restrict__ Wcb, float* __restrict__ stats)
{
    int tid = threadIdx.x;
    if (blockIdx.x == 0) {               // zero 512 stats floats
        stats[tid] = 0.0f;
        stats[256 + tid] = 0.0f;
    }
    int i = blockIdx.x * 256 + tid;      // 63488 total
    if (i < 16384) {
        int n = i >> 7, k = i & 127;
        Wcomb[i] = f2bf(Wv[k * CC + n]);
    } else if (i < 30720) {
        int j = i - 16384; int n = j >> 7, k = j & 127;   // n in 0..111
        Wcomb[16384 + j] = (n < 108) ? f2bf(Wom[k * 108 + n]) : (unsigned short)0;
    } else if (i < 47104) {
        int j = i - 30720; int n = j >> 7, k = j & 127;
        WoT[j] = f2bf(Wo[k * CC + n]);
    } else if (i < 63488) {
        int j = i - 47104;
        Wcb[j] = f2bf(Wc[j]);
    }
}

// ---------------------------------------------------------------------------
// Fused value+om GEMM: [M=16384 x N=240 x K=128]. 256 blocks x 512 threads.
// 8 waves (2/SIMD): wave w -> row-tile (w&3) x col-half (w>>2): 8 or 7 frags.
// Per-output-element MFMA chain identical to the 157us baseline.
// IN_MODE 0: A = x NCHW (transpose in LDS staging).
// IN_MODE 1: A = bn_relu(ybuf) NHWC, bn applied in staging.
// ---------------------------------------------------------------------------
template<int IN_MODE>
__global__ __launch_bounds__(512, 2) void gemm_vom_kernel(
    const float* __restrict__ Ain, const unsigned short* __restrict__ Wcomb,
    const float* __restrict__ bv, const float* __restrict__ bom,
    const float* __restrict__ stats, const float* __restrict__ gamma,
    const float* __restrict__ beta,
    unsigned short* __restrict__ val, float* __restrict__ omb)
{
    __shared__ alignas(16) unsigned short As[64 * 136];
    __shared__ alignas(16) unsigned short Bs[240 * 136];
    __shared__ float bnsc[128], bnsh[128];

    int tid = threadIdx.x;
    int block_m = blockIdx.x * 64;

    if (IN_MODE == 1 && tid < 128) {
        const float inv = 1.0f / 16384.0f;
        float mean = stats[tid] * inv;
        float var  = stats[128 + tid] * inv - mean * mean;
        float sc   = rsqrtf(var + 1e-5f) * gamma[tid];
        bnsc[tid] = sc;
        bnsh[tid] = beta[tid] - mean * sc;
    }

    // stage B: 240 rows x 128 bf16 = 3840 chunks of 8
#pragma unroll
    for (int i = 0; i < 8; i++) {
        int id = tid + i * 512;
        if (id < 3840) {
            int r = id >> 4, kc = id & 15;
            float4 v = *(const float4*)(Wcomb + (size_t)r * CC + kc * 8);
            *(float4*)(&Bs[r * 136 + kc * 8]) = v;
        }
    }

    if (IN_MODE == 0) {
        // A from x NCHW: 128 channels x 16 float4 along hw
        int n   = block_m >> 12;
        int hw0 = block_m & 4095;
#pragma unroll
        for (int i = 0; i < 4; i++) {
            int id = tid + i * 512;          // 0..2047
            int c  = id >> 4, j4 = id & 15;
            float4 v = *(const float4*)(Ain + (((size_t)(n * CC + c)) << 12) + hw0 + j4 * 4);
            As[(j4 * 4 + 0) * 136 + c] = f2bf(v.x);
            As[(j4 * 4 + 1) * 136 + c] = f2bf(v.y);
            As[(j4 * 4 + 2) * 136 + c] = f2bf(v.z);
            As[(j4 * 4 + 3) * 136 + c] = f2bf(v.w);
        }
    } else {
        __syncthreads();                     // bnsc/bnsh ready
#pragma unroll
        for (int i = 0; i < 4; i++) {
            int id = tid + i * 512;          // 0..2047
            int r  = id >> 5, c4 = id & 31;
            float4 v = *(const float4*)(Ain + (size_t)(block_m + r) * CC + c4 * 4);
            int c = c4 * 4;
            float a0 = fmaxf(v.x * bnsc[c + 0] + bnsh[c + 0], 0.0f);
            float a1 = fmaxf(v.y * bnsc[c + 1] + bnsh[c + 1], 0.0f);
            float a2 = fmaxf(v.z * bnsc[c + 2] + bnsh[c + 2], 0.0f);
            float a3 = fmaxf(v.w * bnsc[c + 3] + bnsh[c + 3], 0.0f);
            As[r * 136 + c + 0] = f2bf(a0);
            As[r * 136 + c + 1] = f2bf(a1);
            As[r * 136 + c + 2] = f2bf(a2);
            As[r * 136 + c + 3] = f2bf(a3);
        }
    }
    __syncthreads();

    int w  = tid >> 6;                       // 0..7
    int l  = tid & 63;
    int lr = l & 15, lk = l >> 4;
    int wrow = w & 3;                        // row-tile 0..3
    int wcol = w >> 2;                       // col-half 0..1
    int F  = wcol * 8;                       // first frag
    int NF = wcol ? 7 : 8;                   // frags this wave

    f32x4 acc[8];
#pragma unroll
    for (int nt = 0; nt < 8; nt++) acc[nt] = (f32x4){0.f, 0.f, 0.f, 0.f};

#pragma unroll
    for (int kk = 0; kk < 4; kk++) {
        short8 a = *(const short8*)(&As[(wrow * 16 + lr) * 136 + kk * 32 + lk * 8]);
#pragma unroll
        for (int nt = 0; nt < 8; nt++) {
            if (nt < NF) {
                short8 b = *(const short8*)(&Bs[((F + nt) * 16 + lr) * 136 + kk * 32 + lk * 8]);
                acc[nt] = __builtin_amdgcn_mfma_f32_16x16x32_bf16(a, b, acc[nt], 0, 0, 0);
            }
        }
    }

    int row0 = block_m + wrow * 16 + lk * 4;
#pragma unroll
    for (int nt = 0; nt < 8; nt++) {
        if (nt < NF) {
            int frag = F + nt;
            if (frag < 8) {                  // value output (bf16, +bv)
                int col = frag * 16 + lr;
                float bb = bv[col];
#pragma unroll
                for (int r = 0; r < 4; r++)
                    val[(size_t)(row0 + r) * CC + col] = f2bf(acc[nt][r] + bb);
            } else {                         // offset/mask output (fp32, +bom)
                int ocol = (frag - 8) * 16 + lr;     // 0..111
                float bb = (ocol < 108) ? bom[ocol] : 0.0f;
#pragma unroll
                for (int r = 0; r < 4; r++)
                    omb[(size_t)(row0 + r) * OMP + ocol] = acc[nt][r] + bb;
            }
        }
    }
}

// ---------------------------------------------------------------------------
// Deformable sampling (unchanged from the 157us baseline).
// ---------------------------------------------------------------------------
__global__ __launch_bounds__(256) void sample_kernel(
    const unsigned short* __restrict__ val, const float* __restrict__ omb,
    unsigned int* __restrict__ sbuf)
{
    int tid    = threadIdx.x;
    int gid    = blockIdx.x * 256 + tid;
    int unit   = gid >> 4;                   // 65536 units
    int lane16 = gid & 15;
    int nl = unit >> 2;
    int g  = unit & 3;
    int n  = nl >> 12;
    int hw = nl & 4095;
    int h  = hw >> 6;
    int w  = hw & 63;

    const float* omp = omb + (size_t)nl * OMP + g * 27;
    const unsigned short* vb = val + (((size_t)n) << 19) + g * 32 + lane16 * 2;

    float acc0 = 0.0f, acc1 = 0.0f;
#pragma unroll
    for (int k = 0; k < 9; k++) {
        float ox = omp[2 * k];
        float oy = omp[2 * k + 1];
        float mk = omp[18 + k];
        float ly = (float)(h + k / 3 - 1) + oy;
        float lx = (float)(w + k % 3 - 1) + ox;
        float y0f = floorf(ly), x0f = floorf(lx);
        float wy = ly - y0f, wx = lx - x0f;
        int y0 = (int)y0f, x0 = (int)x0f;

        float v0 = 0.0f, v1 = 0.0f;
#pragma unroll
        for (int cy = 0; cy < 2; cy++) {
#pragma unroll
            for (int cx = 0; cx < 2; cx++) {
                int yi = y0 + cy, xi = x0 + cx;
                float wgt = (cy ? wy : 1.0f - wy) * (cx ? wx : 1.0f - wx);
                bool valid = (yi >= 0) && (yi < HH) && (xi >= 0) && (xi < WW);
                wgt = valid ? wgt : 0.0f;
                int yc = min(max(yi, 0), HH - 1);
                int xc = min(max(xi, 0), WW - 1);
                unsigned int pv = *(const unsigned int*)(vb + (size_t)(yc * WW + xc) * CC);
                v0 += bf2f((unsigned short)(pv & 0xffff)) * wgt;
                v1 += bf2f((unsigned short)(pv >> 16)) * wgt;
            }
        }
        acc0 += mk * v0;
        acc1 += mk * v1;
    }
    unsigned int packed = (unsigned int)f2bf(acc0) | ((unsigned int)f2bf(acc1) << 16);
    sbuf[(size_t)nl * 64 + g * 16 + lane16] = packed;
}

// ---------------------------------------------------------------------------
// Wo GEMM + fused BN-stats: 32-row tile, 512 blocks x 512 threads,
// 44.5 KB LDS -> 2 blocks/CU = 4 waves/SIMD. 8 waves: 2 row-tiles x 4
// col-chunks (16r x 32c each). Same per-element MFMA chain as baseline.
// ---------------------------------------------------------------------------
__global__ __launch_bounds__(512, 4) void gemm_o_bn_kernel(
    const unsigned short* __restrict__ A, const unsigned short* __restrict__ Bt,
    float* __restrict__ ybuf, float* __restrict__ stats)
{
    __shared__ alignas(16) unsigned short As[32 * 136];
    __shared__ alignas(16) unsigned short Bs[128 * 136];
    __shared__ float lstat[256];

    int tid = threadIdx.x;
    int block_m = blockIdx.x * 32;
    if (tid < 256) lstat[tid] = 0.0f;

    {   // stage A: 32 rows x 16 float4 = 512 tasks (1/thread)
        int r = tid >> 4, kc = tid & 15;
        float4 v = *(const float4*)(A + (size_t)(block_m + r) * CC + kc * 8);
        *(float4*)(&As[r * 136 + kc * 8]) = v;
    }
#pragma unroll
    for (int i = 0; i < 4; i++) {
        int id = tid + i * 512;
        int r = id >> 4, kc = id & 15;
        float4 v = *(const float4*)(Bt + (size_t)r * CC + kc * 8);
        *(float4*)(&Bs[r * 136 + kc * 8]) = v;
    }
    __syncthreads();

    int w  = tid >> 6;
    int l  = tid & 63;
    int lr = l & 15, lk = l >> 4;
    int wr = w & 1, wc = w >> 1;             // 2 row-tiles x 4 col-chunks

    f32x4 acc[2];
    acc[0] = (f32x4){0.f, 0.f, 0.f, 0.f};
    acc[1] = (f32x4){0.f, 0.f, 0.f, 0.f};
#pragma unroll
    for (int kk = 0; kk < 4; kk++) {
        short8 a = *(const short8*)(&As[(wr * 16 + lr) * 136 + kk * 32 + lk * 8]);
#pragma unroll
        for (int nt = 0; nt < 2; nt++) {
            short8 b = *(const short8*)(&Bs[(wc * 32 + nt * 16 + lr) * 136 + kk * 32 + lk * 8]);
            acc[nt] = __builtin_amdgcn_mfma_f32_16x16x32_bf16(a, b, acc[nt], 0, 0, 0);
        }
    }

    int row0 = block_m + wr * 16 + lk * 4;
#pragma unroll
    for (int nt = 0; nt < 2; nt++) {
        int col = wc * 32 + nt * 16 + lr;
        float s = 0.0f, sq = 0.0f;
#pragma unroll
        for (int r = 0; r < 4; r++) {
            float v = acc[nt][r];
            ybuf[(size_t)(row0 + r) * CC + col] = v;
            s += v;
            sq += v * v;
        }
        atomicAdd(&lstat[col], s);
        atomicAdd(&lstat[128 + col], sq);
    }
    __syncthreads();
    if (tid < 128) {
        atomicAdd(&stats[tid], lstat[tid]);
        atomicAdd(&stats[128 + tid], lstat[128 + tid]);
    }
}

// ---------------------------------------------------------------------------
// Final GEMM: A = bn(ybuf) + x_residual(NCHW), B = Wc; out NCHW fp32.
// 256 blocks x 512 threads (8 waves, 2/SIMD): 4 row-tiles x 2 col-halves.
// ---------------------------------------------------------------------------
__global__ __launch_bounds__(512, 2) void gemm_final_kernel(
    const float* __restrict__ ybuf, const float* __restrict__ x,
    const unsigned short* __restrict__ Bt, const float* __restrict__ stats,
    const float* __restrict__ gamma, const float* __restrict__ beta,
    float* __restrict__ out)
{
    __shared__ alignas(16) unsigned short As[64 * 136];
    __shared__ alignas(16) unsigned short Bs[128 * 136];
    __shared__ alignas(16) float Xs[64 * 132];
    __shared__ float bnsc[128], bnsh[128];

    int tid = threadIdx.x;
    int block_m = blockIdx.x * 64;
    int n   = block_m >> 12;
    int hw0 = block_m & 4095;

    if (tid < 128) {
        const float inv = 1.0f / 16384.0f;
        float mean = stats[tid] * inv;
        float var  = stats[128 + tid] * inv - mean * mean;
        float sc   = rsqrtf(var + 1e-5f) * gamma[tid];
        bnsc[tid] = sc;
        bnsh[tid] = beta[tid] - mean * sc;
    }

    // stage x residual (NCHW -> LDS transpose, fp32)
#pragma unroll
    for (int i = 0; i < 4; i++) {
        int id = tid + i * 512;
        int c  = id >> 4, j4 = id & 15;
        float4 v = *(const float4*)(x + (((size_t)(n * CC + c)) << 12) + hw0 + j4 * 4);
        Xs[(j4 * 4 + 0) * 132 + c] = v.x;
        Xs[(j4 * 4 + 1) * 132 + c] = v.y;
        Xs[(j4 * 4 + 2) * 132 + c] = v.z;
        Xs[(j4 * 4 + 3) * 132 + c] = v.w;
    }
    // stage B
#pragma unroll
    for (int i = 0; i < 4; i++) {
        int id = tid + i * 512;
        int r = id >> 4, kc = id & 15;
        float4 v = *(const float4*)(Bt + (size_t)r * CC + kc * 8);
        *(float4*)(&Bs[r * 136 + kc * 8]) = v;
    }
    __syncthreads();

    // stage A = bn(ybuf) + Xs
#pragma unroll
    for (int i = 0; i < 4; i++) {
        int id = tid + i * 512;
        int r  = id >> 5, c4 = id & 31;
        float4 v = *(const float4*)(ybuf + (size_t)(block_m + r) * CC + c4 * 4);
        int c = c4 * 4;
        float a0 = v.x * bnsc[c + 0] + bnsh[c + 0] + Xs[r * 132 + c + 0];
        float a1 = v.y * bnsc[c + 1] + bnsh[c + 1] + Xs[r * 132 + c + 1];
        float a2 = v.z * bnsc[c + 2] + bnsh[c + 2] + Xs[r * 132 + c + 2];
        float a3 = v.w * bnsc[c + 3] + bnsh[c + 3] + Xs[r * 132 + c + 3];
        As[r * 136 + c + 0] = f2bf(a0);
        As[r * 136 + c + 1] = f2bf(a1);
        As[r * 136 + c + 2] = f2bf(a2);
        As[r * 136 + c + 3] = f2bf(a3);
    }
    __syncthreads();

    int w  = tid >> 6;
    int l  = tid & 63;
    int lr = l & 15, lk = l >> 4;
    int wr = w & 3, wc = w >> 2;             // 4 row-tiles x 2 col-halves

    f32x4 acc[4];
#pragma unroll
    for (int nt = 0; nt < 4; nt++) acc[nt] = (f32x4){0.f, 0.f, 0.f, 0.f};

#pragma unroll
    for (int kk = 0; kk < 4; kk++) {
        short8 a = *(const short8*)(&As[(wr * 16 + lr) * 136 + kk * 32 + lk * 8]);
#pragma unroll
        for (int nt = 0; nt < 4; nt++) {
            short8 b = *(const short8*)(&Bs[(wc * 64 + nt * 16 + lr) * 136 + kk * 32 + lk * 8]);
            acc[nt] = __builtin_amdgcn_mfma_f32_16x16x32_bf16(a, b, acc[nt], 0, 0, 0);
        }
    }

    // NCHW scatter via LDS transpose (reuse Bs as float[128][68])
    __syncthreads();
    float* T = (float*)Bs;
    int rloc = wr * 16 + lk * 4;
#pragma unroll
    for (int nt = 0; nt < 4; nt++) {
        int col = wc * 64 + nt * 16 + lr;
#pragma unroll
        for (int r = 0; r < 4; r++)
            T[col * 68 + rloc + r] = acc[nt][r];
    }
    __syncthreads();
    int o = tid >> 2, q = tid & 3;
    float* op = out + (((size_t)(n * CC + o)) << 12) + hw0 + q * 16;
#pragma unroll
    for (int i = 0; i < 4; i++) {
        float4 v = *(const float4*)(&T[o * 68 + q * 16 + i * 4]);
        *(float4*)(op + i * 4) = v;
    }
}

// ---------------------------------------------------------------------------
extern "C" void kernel_launch(void* const* d_in, const int* in_sizes, int n_in,
                              void* d_out, int out_size, void* d_ws, size_t ws_size,
                              hipStream_t stream)
{
    const float* x     = (const float*)d_in[0];
    const float* Wv    = (const float*)d_in[1];
    const float* bv    = (const float*)d_in[2];
    const float* Wom   = (const float*)d_in[3];
    const float* bom   = (const float*)d_in[4];
    const float* Wo    = (const float*)d_in[5];
    const float* gamma = (const float*)d_in[6];
    const float* beta  = (const float*)d_in[7];
    const float* Wc    = (const float*)d_in[8];
    float* out = (float*)d_out;

    char* ws = (char*)d_ws;
    unsigned short* val   = (unsigned short*)ws;   ws += (size_t)NL * CC * 2;    // 4 MB
    float*          omb   = (float*)ws;            ws += (size_t)NL * OMP * 4;   // 7.34 MB
    unsigned int*   sbuf  = (unsigned int*)ws;     ws += (size_t)NL * CC * 2;    // 4 MB
    float*          ybuf  = (float*)ws;            ws += (size_t)NL * CC * 4;    // 8 MB
    unsigned short* Wcomb = (unsigned short*)ws;   ws += 240 * 128 * 2;
    unsigned short* WoT   = (unsigned short*)ws;   ws += 128 * 128 * 2;
    unsigned short* Wcb   = (unsigned short*)ws;   ws += 128 * 128 * 2;
    float*          stats = (float*)ws;            ws += 2048;

    dim3 b256(256), b512(512);

    prep_kernel<<<248, b256, 0, stream>>>(Wv, Wom, Wo, Wc, Wcomb, WoT, Wcb, stats);

    // ---- DCN block 1 ----
    gemm_vom_kernel<0><<<256, b512, 0, stream>>>(x, Wcomb, bv, bom,
                                                 nullptr, nullptr, nullptr, val, omb);
    sample_kernel<<<4096, b256, 0, stream>>>(val, omb, sbuf);
    gemm_o_bn_kernel<<<512, b512, 0, stream>>>((const unsigned short*)sbuf, WoT, ybuf, stats);

    // ---- DCN block 2 (bn+relu fused into A-staging) ----
    gemm_vom_kernel<1><<<256, b512, 0, stream>>>(ybuf, Wcomb, bv, bom,
                                                 stats, gamma, beta, val, omb);
    sample_kernel<<<4096, b256, 0, stream>>>(val, omb, sbuf);
    gemm_o_bn_kernel<<<512, b512, 0, stream>>>((const unsigned short*)sbuf, WoT, ybuf, stats + 256);

    // ---- final: bn2 + residual + 1x1 conv, NCHW out ----
    gemm_final_kernel<<<256, b512, 0, stream>>>(ybuf, x, Wcb, stats + 256, gamma, beta, out);
}

// Round 5
// 153.120 us; speedup vs baseline: 8.9073x; 1.1297x over previous
//
#include <hip/hip_runtime.h>
#include <math.h>

// Problem constants
#define CC   128         // channels
#define NL   16384       // N * H * W = 4*64*64
#define LHW  4096        // H*W
#define OMP  112         // padded om row stride (108 real cols)
#define HH   64
#define WW   64

typedef __attribute__((ext_vector_type(8))) short short8;
typedef __attribute__((ext_vector_type(4))) float f32x4;

__device__ __forceinline__ unsigned short f2bf(float f) {
    union { float f; unsigned u; } v; v.f = f;
    unsigned r = v.u + 0x7fff + ((v.u >> 16) & 1);   // RNE
    return (unsigned short)(r >> 16);
}
__device__ __forceinline__ float bf2f(unsigned short u) {
    union { unsigned u; float f; } v; v.u = ((unsigned)u) << 16;
    return v.f;
}

// ---------------------------------------------------------------------------
// Weight prep + stats zero.
// Wcomb[240][128] bf16: rows 0..127 = Wv^T, rows 128..239 = Wom^T (pad 108->112)
// WoT[128][128] = Wo^T ; Wcb[128][128] = Wc (already Bt layout: [o][c]).
// ---------------------------------------------------------------------------
__global__ __launch_bounds__(256) void prep_kernel(
    const float* __restrict__ Wv, const float* __restrict__ Wom,
    const float* __restrict__ Wo, const float* __restrict__ Wc,
    unsigned short* __restrict__ Wcomb, unsigned short* __restrict__ WoT,
    unsigned short* __restrict__ Wcb, float* __restrict__ stats)
{
    int tid = threadIdx.x;
    if (blockIdx.x == 0) {               // zero 512 stats floats
        stats[tid] = 0.0f;
        stats[256 + tid] = 0.0f;
    }
    int i = blockIdx.x * 256 + tid;      // 63488 total
    if (i < 16384) {
        int n = i >> 7, k = i & 127;
        Wcomb[i] = f2bf(Wv[k * CC + n]);
    } else if (i < 30720) {
        int j = i - 16384; int n = j >> 7, k = j & 127;   // n in 0..111
        Wcomb[16384 + j] = (n < 108) ? f2bf(Wom[k * 108 + n]) : (unsigned short)0;
    } else if (i < 47104) {
        int j = i - 30720; int n = j >> 7, k = j & 127;
        WoT[j] = f2bf(Wo[k * CC + n]);
    } else if (i < 63488) {
        int j = i - 47104;
        Wcb[j] = f2bf(Wc[j]);
    }
}

// ---------------------------------------------------------------------------
// Fused value+om GEMM: [M=16384 x N=240 x K=128].
// IN_MODE 0: A = x in NCHW (transpose in LDS staging).
// IN_MODE 1: A = bn_relu(ybuf) (NHWC), stats/gamma/beta applied in staging.
// Outputs: val bf16 [M][128] (+bv), omb fp32 [M][112] (+bom, cols<108).
// 4 waves; wave w computes rows w*16..w*16+15 x all 240 cols (15 frags).
// ---------------------------------------------------------------------------
template<int IN_MODE>
__global__ __launch_bounds__(256) void gemm_vom_kernel(
    const float* __restrict__ Ain, const unsigned short* __restrict__ Wcomb,
    const float* __restrict__ bv, const float* __restrict__ bom,
    const float* __restrict__ stats, const float* __restrict__ gamma,
    const float* __restrict__ beta,
    unsigned short* __restrict__ val, float* __restrict__ omb)
{
    __shared__ unsigned short As[64 * 136];
    __shared__ unsigned short Bs[240 * 136];
    __shared__ float bnsc[128], bnsh[128];

    int tid = threadIdx.x;
    int block_m = blockIdx.x * 64;

    if (IN_MODE == 1 && tid < 128) {
        const float inv = 1.0f / 16384.0f;
        float mean = stats[tid] * inv;
        float var  = stats[128 + tid] * inv - mean * mean;
        float sc   = rsqrtf(var + 1e-5f) * gamma[tid];
        bnsc[tid] = sc;
        bnsh[tid] = beta[tid] - mean * sc;
    }

    // stage B: 240 rows x 128 bf16 = 3840 chunks of 8  (15 x 256, exact)
#pragma unroll
    for (int i = 0; i < 15; i++) {
        int id = tid + i * 256;
        int r = id >> 4, kc = id & 15;
        float4 v = *(const float4*)(Wcomb + (size_t)r * CC + kc * 8);
        *(float4*)(&Bs[r * 136 + kc * 8]) = v;
    }

    if (IN_MODE == 0) {
        // A from x NCHW: 128 channels x 16 float4 along hw
        int n   = block_m >> 12;
        int hw0 = block_m & 4095;
#pragma unroll
        for (int i = 0; i < 8; i++) {
            int id = tid + i * 256;          // 0..2047
            int c  = id >> 4, j4 = id & 15;
            float4 v = *(const float4*)(Ain + (((size_t)(n * CC + c)) << 12) + hw0 + j4 * 4);
            As[(j4 * 4 + 0) * 136 + c] = f2bf(v.x);
            As[(j4 * 4 + 1) * 136 + c] = f2bf(v.y);
            As[(j4 * 4 + 2) * 136 + c] = f2bf(v.z);
            As[(j4 * 4 + 3) * 136 + c] = f2bf(v.w);
        }
    } else {
        __syncthreads();                     // bnsc/bnsh ready
#pragma unroll
        for (int i = 0; i < 8; i++) {
            int id = tid + i * 256;          // 0..2047
            int r  = id >> 5, c4 = id & 31;
            float4 v = *(const float4*)(Ain + (size_t)(block_m + r) * CC + c4 * 4);
            int c = c4 * 4;
            float a0 = fmaxf(v.x * bnsc[c + 0] + bnsh[c + 0], 0.0f);
            float a1 = fmaxf(v.y * bnsc[c + 1] + bnsh[c + 1], 0.0f);
            float a2 = fmaxf(v.z * bnsc[c + 2] + bnsh[c + 2], 0.0f);
            float a3 = fmaxf(v.w * bnsc[c + 3] + bnsh[c + 3], 0.0f);
            As[r * 136 + c + 0] = f2bf(a0);
            As[r * 136 + c + 1] = f2bf(a1);
            As[r * 136 + c + 2] = f2bf(a2);
            As[r * 136 + c + 3] = f2bf(a3);
        }
    }
    __syncthreads();

    int w  = tid >> 6;
    int l  = tid & 63;
    int lr = l & 15, lk = l >> 4;

    f32x4 acc[15];
#pragma unroll
    for (int nt = 0; nt < 15; nt++) acc[nt] = (f32x4){0.f, 0.f, 0.f, 0.f};

#pragma unroll
    for (int kk = 0; kk < 4; kk++) {
        short8 a = *(const short8*)(&As[(w * 16 + lr) * 136 + kk * 32 + lk * 8]);
#pragma unroll
        for (int nt = 0; nt < 15; nt++) {
            short8 b = *(const short8*)(&Bs[(nt * 16 + lr) * 136 + kk * 32 + lk * 8]);
            acc[nt] = __builtin_amdgcn_mfma_f32_16x16x32_bf16(a, b, acc[nt], 0, 0, 0);
        }
    }

    int row0 = block_m + w * 16 + lk * 4;
#pragma unroll
    for (int nt = 0; nt < 8; nt++) {
        int col = nt * 16 + lr;
        float bb = bv[col];
#pragma unroll
        for (int r = 0; r < 4; r++)
            val[(size_t)(row0 + r) * CC + col] = f2bf(acc[nt][r] + bb);
    }
#pragma unroll
    for (int nt = 8; nt < 15; nt++) {
        int col = (nt - 8) * 16 + lr;        // 0..111
        float bb = (col < 108) ? bom[col] : 0.0f;
#pragma unroll
        for (int r = 0; r < 4; r++)
            omb[(size_t)(row0 + r) * OMP + col] = acc[nt][r] + bb;
    }
}

// ---------------------------------------------------------------------------
// Deformable sampling (bf16 value): 8 lanes per (nl,g) unit, 4 channels/lane
// (was 16 lanes x 2 ch). Halves om-load redundancy and per-unit weight VALU;
// val gathers widen to dwordx2 (same 64B line per corner, half the issues).
// Per-channel accumulation chains (corner order, k order) are bit-identical
// to the 157us-verified baseline.
// ---------------------------------------------------------------------------
__global__ __launch_bounds__(256) void sample_kernel(
    const unsigned short* __restrict__ val, const float* __restrict__ omb,
    unsigned int* __restrict__ sbuf)
{
    int tid   = threadIdx.x;
    int gid   = blockIdx.x * 256 + tid;
    int unit  = gid >> 3;                    // 65536 units
    int lane8 = gid & 7;
    int nl = unit >> 2;
    int g  = unit & 3;
    int n  = nl >> 12;
    int hw = nl & 4095;
    int h  = hw >> 6;
    int w  = hw & 63;

    const float* omp = omb + (size_t)nl * OMP + g * 27;
    const unsigned short* vb = val + (((size_t)n) << 19) + g * 32 + lane8 * 4;

    float acc0 = 0.0f, acc1 = 0.0f, acc2 = 0.0f, acc3 = 0.0f;
#pragma unroll
    for (int k = 0; k < 9; k++) {
        float ox = omp[2 * k];
        float oy = omp[2 * k + 1];
        float mk = omp[18 + k];
        float ly = (float)(h + k / 3 - 1) + oy;
        float lx = (float)(w + k % 3 - 1) + ox;
        float y0f = floorf(ly), x0f = floorf(lx);
        float wy = ly - y0f, wx = lx - x0f;
        int y0 = (int)y0f, x0 = (int)x0f;

        float v0 = 0.0f, v1 = 0.0f, v2 = 0.0f, v3 = 0.0f;
#pragma unroll
        for (int cy = 0; cy < 2; cy++) {
#pragma unroll
            for (int cx = 0; cx < 2; cx++) {
                int yi = y0 + cy, xi = x0 + cx;
                float wgt = (cy ? wy : 1.0f - wy) * (cx ? wx : 1.0f - wx);
                bool valid = (yi >= 0) && (yi < HH) && (xi >= 0) && (xi < WW);
                wgt = valid ? wgt : 0.0f;
                int yc = min(max(yi, 0), HH - 1);
                int xc = min(max(xi, 0), WW - 1);
                uint2 pv = *(const uint2*)(vb + (size_t)(yc * WW + xc) * CC);
                v0 += bf2f((unsigned short)(pv.x & 0xffff)) * wgt;
                v1 += bf2f((unsigned short)(pv.x >> 16)) * wgt;
                v2 += bf2f((unsigned short)(pv.y & 0xffff)) * wgt;
                v3 += bf2f((unsigned short)(pv.y >> 16)) * wgt;
            }
        }
        acc0 += mk * v0;
        acc1 += mk * v1;
        acc2 += mk * v2;
        acc3 += mk * v3;
    }
    uint2 packed;
    packed.x = (unsigned int)f2bf(acc0) | ((unsigned int)f2bf(acc1) << 16);
    packed.y = (unsigned int)f2bf(acc2) | ((unsigned int)f2bf(acc3) << 16);
    *(uint2*)(&sbuf[(size_t)nl * 64 + g * 16 + lane8 * 2]) = packed;
}

// ---------------------------------------------------------------------------
// Wo GEMM + fused BN-stats: ybuf = sbuf @ Wo ; stats[c] += sum, stats[128+c] += sumsq
// 2x2 wave grid, 64-row tile.
// ---------------------------------------------------------------------------
__global__ __launch_bounds__(256) void gemm_o_bn_kernel(
    const unsigned short* __restrict__ A, const unsigned short* __restrict__ Bt,
    float* __restrict__ ybuf, float* __restrict__ stats)
{
    __shared__ unsigned short As[64 * 136];
    __shared__ unsigned short Bs[128 * 136];
    __shared__ float lstat[256];

    int tid = threadIdx.x;
    int block_m = blockIdx.x * 64;
    lstat[tid] = 0.0f;

#pragma unroll
    for (int i = 0; i < 4; i++) {
        int id = tid + i * 256;
        int r = id >> 4, kc = id & 15;
        float4 v = *(const float4*)(A + (size_t)(block_m + r) * CC + kc * 8);
        *(float4*)(&As[r * 136 + kc * 8]) = v;
    }
#pragma unroll
    for (int i = 0; i < 8; i++) {
        int id = tid + i * 256;
        int r = id >> 4, kc = id & 15;
        float4 v = *(const float4*)(Bt + (size_t)r * CC + kc * 8);
        *(float4*)(&Bs[r * 136 + kc * 8]) = v;
    }
    __syncthreads();

    int w  = tid >> 6;
    int l  = tid & 63;
    int wm = w & 1, wn = w >> 1;
    int lr = l & 15, lk = l >> 4;

    f32x4 acc[2][4];
#pragma unroll
    for (int mt = 0; mt < 2; mt++)
#pragma unroll
        for (int nt = 0; nt < 4; nt++) acc[mt][nt] = (f32x4){0.f, 0.f, 0.f, 0.f};

#pragma unroll
    for (int kk = 0; kk < 4; kk++) {
        short8 a[2], b[4];
#pragma unroll
        for (int mt = 0; mt < 2; mt++)
            a[mt] = *(const short8*)(&As[(wm * 32 + mt * 16 + lr) * 136 + kk * 32 + lk * 8]);
#pragma unroll
        for (int nt = 0; nt < 4; nt++)
            b[nt] = *(const short8*)(&Bs[(wn * 64 + nt * 16 + lr) * 136 + kk * 32 + lk * 8]);
#pragma unroll
        for (int mt = 0; mt < 2; mt++)
#pragma unroll
            for (int nt = 0; nt < 4; nt++)
                acc[mt][nt] = __builtin_amdgcn_mfma_f32_16x16x32_bf16(
                    a[mt], b[nt], acc[mt][nt], 0, 0, 0);
    }

    // write + per-lane stats
#pragma unroll
    for (int nt = 0; nt < 4; nt++) {
        int col = wn * 64 + nt * 16 + lr;
        float s = 0.0f, sq = 0.0f;
#pragma unroll
        for (int mt = 0; mt < 2; mt++) {
            int row0 = block_m + wm * 32 + mt * 16 + lk * 4;
#pragma unroll
            for (int r = 0; r < 4; r++) {
                float v = acc[mt][nt][r];
                ybuf[(size_t)(row0 + r) * CC + col] = v;
                s += v;
                sq += v * v;
            }
        }
        atomicAdd(&lstat[col], s);
        atomicAdd(&lstat[128 + col], sq);
    }
    __syncthreads();
    if (tid < 128) {
        atomicAdd(&stats[tid], lstat[tid]);
        atomicAdd(&stats[128 + tid], lstat[128 + tid]);
    }
}

// ---------------------------------------------------------------------------
// Final GEMM: A = bn(ybuf) + x_residual(NCHW), B = Wc; out NCHW fp32.
// ---------------------------------------------------------------------------
__global__ __launch_bounds__(256) void gemm_final_kernel(
    const float* __restrict__ ybuf, const float* __restrict__ x,
    const unsigned short* __restrict__ Bt, const float* __restrict__ stats,
    const float* __restrict__ gamma, const float* __restrict__ beta,
    float* __restrict__ out)
{
    __shared__ unsigned short As[64 * 136];
    __shared__ unsigned short Bs[128 * 136];
    __shared__ float Xs[64 * 132];
    __shared__ float bnsc[128], bnsh[128];

    int tid = threadIdx.x;
    int block_m = blockIdx.x * 64;
    int n   = block_m >> 12;
    int hw0 = block_m & 4095;

    if (tid < 128) {
        const float inv = 1.0f / 16384.0f;
        float mean = stats[tid] * inv;
        float var  = stats[128 + tid] * inv - mean * mean;
        float sc   = rsqrtf(var + 1e-5f) * gamma[tid];
        bnsc[tid] = sc;
        bnsh[tid] = beta[tid] - mean * sc;
    }

    // stage x residual (NCHW -> LDS transpose, fp32)
#pragma unroll
    for (int i = 0; i < 8; i++) {
        int id = tid + i * 256;
        int c  = id >> 4, j4 = id & 15;
        float4 v = *(const float4*)(x + (((size_t)(n * CC + c)) << 12) + hw0 + j4 * 4);
        Xs[(j4 * 4 + 0) * 132 + c] = v.x;
        Xs[(j4 * 4 + 1) * 132 + c] = v.y;
        Xs[(j4 * 4 + 2) * 132 + c] = v.z;
        Xs[(j4 * 4 + 3) * 132 + c] = v.w;
    }
    // stage B
#pragma unroll
    for (int i = 0; i < 8; i++) {
        int id = tid + i * 256;
        int r = id >> 4, kc = id & 15;
        float4 v = *(const float4*)(Bt + (size_t)r * CC + kc * 8);
        *(float4*)(&Bs[r * 136 + kc * 8]) = v;
    }
    __syncthreads();

    // stage A = bn(ybuf) + Xs
#pragma unroll
    for (int i = 0; i < 8; i++) {
        int id = tid + i * 256;
        int r  = id >> 5, c4 = id & 31;
        float4 v = *(const float4*)(ybuf + (size_t)(block_m + r) * CC + c4 * 4);
        int c = c4 * 4;
        float a0 = v.x * bnsc[c + 0] + bnsh[c + 0] + Xs[r * 132 + c + 0];
        float a1 = v.y * bnsc[c + 1] + bnsh[c + 1] + Xs[r * 132 + c + 1];
        float a2 = v.z * bnsc[c + 2] + bnsh[c + 2] + Xs[r * 132 + c + 2];
        float a3 = v.w * bnsc[c + 3] + bnsh[c + 3] + Xs[r * 132 + c + 3];
        As[r * 136 + c + 0] = f2bf(a0);
        As[r * 136 + c + 1] = f2bf(a1);
        As[r * 136 + c + 2] = f2bf(a2);
        As[r * 136 + c + 3] = f2bf(a3);
    }
    __syncthreads();

    int w  = tid >> 6;
    int l  = tid & 63;
    int wm = w & 1, wn = w >> 1;
    int lr = l & 15, lk = l >> 4;

    f32x4 acc[2][4];
#pragma unroll
    for (int mt = 0; mt < 2; mt++)
#pragma unroll
        for (int nt = 0; nt < 4; nt++) acc[mt][nt] = (f32x4){0.f, 0.f, 0.f, 0.f};

#pragma unroll
    for (int kk = 0; kk < 4; kk++) {
        short8 a[2], b[4];
#pragma unroll
        for (int mt = 0; mt < 2; mt++)
            a[mt] = *(const short8*)(&As[(wm * 32 + mt * 16 + lr) * 136 + kk * 32 + lk * 8]);
#pragma unroll
        for (int nt = 0; nt < 4; nt++)
            b[nt] = *(const short8*)(&Bs[(wn * 64 + nt * 16 + lr) * 136 + kk * 32 + lk * 8]);
#pragma unroll
        for (int mt = 0; mt < 2; mt++)
#pragma unroll
            for (int nt = 0; nt < 4; nt++)
                acc[mt][nt] = __builtin_amdgcn_mfma_f32_16x16x32_bf16(
                    a[mt], b[nt], acc[mt][nt], 0, 0, 0);
    }

    // NCHW scatter via LDS transpose (reuse Bs as float[128][68])
    __syncthreads();
    float* T = (float*)Bs;
#pragma unroll
    for (int mt = 0; mt < 2; mt++) {
        int rloc = wm * 32 + mt * 16 + lk * 4;
#pragma unroll
        for (int nt = 0; nt < 4; nt++) {
            int col = wn * 64 + nt * 16 + lr;
#pragma unroll
            for (int r = 0; r < 4; r++)
                T[col * 68 + rloc + r] = acc[mt][nt][r];
        }
    }
    __syncthreads();
    int o = tid >> 1, half = tid & 1;
    float* op = out + (((size_t)(n * CC + o)) << 12) + hw0 + half * 32;
#pragma unroll
    for (int i = 0; i < 8; i++) {
        float4 v = *(const float4*)(&T[o * 68 + half * 32 + i * 4]);
        *(float4*)(op + i * 4) = v;
    }
}

// ---------------------------------------------------------------------------
extern "C" void kernel_launch(void* const* d_in, const int* in_sizes, int n_in,
                              void* d_out, int out_size, void* d_ws, size_t ws_size,
                              hipStream_t stream)
{
    const float* x     = (const float*)d_in[0];
    const float* Wv    = (const float*)d_in[1];
    const float* bv    = (const float*)d_in[2];
    const float* Wom   = (const float*)d_in[3];
    const float* bom   = (const float*)d_in[4];
    const float* Wo    = (const float*)d_in[5];
    const float* gamma = (const float*)d_in[6];
    const float* beta  = (const float*)d_in[7];
    const float* Wc    = (const float*)d_in[8];
    float* out = (float*)d_out;

    char* ws = (char*)d_ws;
    unsigned short* val   = (unsigned short*)ws;   ws += (size_t)NL * CC * 2;    // 4 MB
    float*          omb   = (float*)ws;            ws += (size_t)NL * OMP * 4;   // 7.34 MB
    unsigned int*   sbuf  = (unsigned int*)ws;     ws += (size_t)NL * CC * 2;    // 4 MB
    float*          ybuf  = (float*)ws;            ws += (size_t)NL * CC * 4;    // 8 MB
    unsigned short* Wcomb = (unsigned short*)ws;   ws += 240 * 128 * 2;
    unsigned short* WoT   = (unsigned short*)ws;   ws += 128 * 128 * 2;
    unsigned short* Wcb   = (unsigned short*)ws;   ws += 128 * 128 * 2;
    float*          stats = (float*)ws;            ws += 2048;

    dim3 b256(256);

    prep_kernel<<<248, b256, 0, stream>>>(Wv, Wom, Wo, Wc, Wcomb, WoT, Wcb, stats);

    // ---- DCN block 1 ----
    gemm_vom_kernel<0><<<256, b256, 0, stream>>>(x, Wcomb, bv, bom,
                                                 nullptr, nullptr, nullptr, val, omb);
    sample_kernel<<<2048, b256, 0, stream>>>(val, omb, sbuf);
    gemm_o_bn_kernel<<<256, b256, 0, stream>>>((const unsigned short*)sbuf, WoT, ybuf, stats);

    // ---- DCN block 2 (bn+relu fused into A-staging) ----
    gemm_vom_kernel<1><<<256, b256, 0, stream>>>(ybuf, Wcomb, bv, bom,
                                                 stats, gamma, beta, val, omb);
    sample_kernel<<<2048, b256, 0, stream>>>(val, omb, sbuf);
    gemm_o_bn_kernel<<<256, b256, 0, stream>>>((const unsigned short*)sbuf, WoT, ybuf, stats + 256);

    // ---- final: bn2 + residual + 1x1 conv, NCHW out ----
    gemm_final_kernel<<<256, b256, 0, stream>>>(ybuf, x, Wcb, stats + 256, gamma, beta, out);
}

// Round 6
// 148.898 us; speedup vs baseline: 9.1598x; 1.0284x over previous
//
#include <hip/hip_runtime.h>
#include <math.h>

// Problem constants
#define CC   128         // channels
#define NL   16384       // N * H * W = 4*64*64
#define LHW  4096        // H*W
#define OMP  112         // padded om row stride (108 real cols)
#define HH   64
#define WW   64

typedef __attribute__((ext_vector_type(8))) short short8;
typedef __attribute__((ext_vector_type(4))) float f32x4;

__device__ __forceinline__ unsigned short f2bf(float f) {
    union { float f; unsigned u; } v; v.f = f;
    unsigned r = v.u + 0x7fff + ((v.u >> 16) & 1);   // RNE
    return (unsigned short)(r >> 16);
}
__device__ __forceinline__ float bf2f(unsigned short u) {
    union { unsigned u; float f; } v; v.u = ((unsigned)u) << 16;
    return v.f;
}

// ---------------------------------------------------------------------------
// Weight prep + stats zero.
// Wcomb[240][128] bf16: rows 0..127 = Wv^T, rows 128..239 = Wom^T (pad 108->112)
// WoT[128][128] = Wo^T ; Wcb[128][128] = Wc (already Bt layout: [o][c]).
// ---------------------------------------------------------------------------
__global__ __launch_bounds__(256) void prep_kernel(
    const float* __restrict__ Wv, const float* __restrict__ Wom,
    const float* __restrict__ Wo, const float* __restrict__ Wc,
    unsigned short* __restrict__ Wcomb, unsigned short* __restrict__ WoT,
    unsigned short* __restrict__ Wcb, float* __restrict__ stats)
{
    int tid = threadIdx.x;
    if (blockIdx.x == 0) {               // zero 512 stats floats
        stats[tid] = 0.0f;
        stats[256 + tid] = 0.0f;
    }
    int i = blockIdx.x * 256 + tid;      // 63488 total
    if (i < 16384) {
        int n = i >> 7, k = i & 127;
        Wcomb[i] = f2bf(Wv[k * CC + n]);
    } else if (i < 30720) {
        int j = i - 16384; int n = j >> 7, k = j & 127;   // n in 0..111
        Wcomb[16384 + j] = (n < 108) ? f2bf(Wom[k * 108 + n]) : (unsigned short)0;
    } else if (i < 47104) {
        int j = i - 30720; int n = j >> 7, k = j & 127;
        WoT[j] = f2bf(Wo[k * CC + n]);
    } else if (i < 63488) {
        int j = i - 47104;
        Wcb[j] = f2bf(Wc[j]);
    }
}

// ---------------------------------------------------------------------------
// Fused value+om GEMM: [M=16384 x N=240 x K=128].
// IN_MODE 0: A = x in NCHW (transpose in LDS staging).
// IN_MODE 1: A = bn_relu(ybuf) (NHWC), stats/gamma/beta applied in staging.
// Outputs: val bf16 [M][128] (+bv), omb fp32 [M][112] (+bom, cols<108).
// 4 waves; wave w computes rows w*16..w*16+15 x all 240 cols (15 frags).
// ---------------------------------------------------------------------------
template<int IN_MODE>
__global__ __launch_bounds__(256) void gemm_vom_kernel(
    const float* __restrict__ Ain, const unsigned short* __restrict__ Wcomb,
    const float* __restrict__ bv, const float* __restrict__ bom,
    const float* __restrict__ stats, const float* __restrict__ gamma,
    const float* __restrict__ beta,
    unsigned short* __restrict__ val, float* __restrict__ omb)
{
    __shared__ unsigned short As[64 * 136];
    __shared__ unsigned short Bs[240 * 136];
    __shared__ float bnsc[128], bnsh[128];

    int tid = threadIdx.x;
    int block_m = blockIdx.x * 64;

    if (IN_MODE == 1 && tid < 128) {
        const float inv = 1.0f / 16384.0f;
        float mean = stats[tid] * inv;
        float var  = stats[128 + tid] * inv - mean * mean;
        float sc   = rsqrtf(var + 1e-5f) * gamma[tid];
        bnsc[tid] = sc;
        bnsh[tid] = beta[tid] - mean * sc;
    }

    // stage B: 240 rows x 128 bf16 = 3840 chunks of 8  (15 x 256, exact)
#pragma unroll
    for (int i = 0; i < 15; i++) {
        int id = tid + i * 256;
        int r = id >> 4, kc = id & 15;
        float4 v = *(const float4*)(Wcomb + (size_t)r * CC + kc * 8);
        *(float4*)(&Bs[r * 136 + kc * 8]) = v;
    }

    if (IN_MODE == 0) {
        // A from x NCHW: 128 channels x 16 float4 along hw
        int n   = block_m >> 12;
        int hw0 = block_m & 4095;
#pragma unroll
        for (int i = 0; i < 8; i++) {
            int id = tid + i * 256;          // 0..2047
            int c  = id >> 4, j4 = id & 15;
            float4 v = *(const float4*)(Ain + (((size_t)(n * CC + c)) << 12) + hw0 + j4 * 4);
            As[(j4 * 4 + 0) * 136 + c] = f2bf(v.x);
            As[(j4 * 4 + 1) * 136 + c] = f2bf(v.y);
            As[(j4 * 4 + 2) * 136 + c] = f2bf(v.z);
            As[(j4 * 4 + 3) * 136 + c] = f2bf(v.w);
        }
    } else {
        __syncthreads();                     // bnsc/bnsh ready
#pragma unroll
        for (int i = 0; i < 8; i++) {
            int id = tid + i * 256;          // 0..2047
            int r  = id >> 5, c4 = id & 31;
            float4 v = *(const float4*)(Ain + (size_t)(block_m + r) * CC + c4 * 4);
            int c = c4 * 4;
            float a0 = fmaxf(v.x * bnsc[c + 0] + bnsh[c + 0], 0.0f);
            float a1 = fmaxf(v.y * bnsc[c + 1] + bnsh[c + 1], 0.0f);
            float a2 = fmaxf(v.z * bnsc[c + 2] + bnsh[c + 2], 0.0f);
            float a3 = fmaxf(v.w * bnsc[c + 3] + bnsh[c + 3], 0.0f);
            As[r * 136 + c + 0] = f2bf(a0);
            As[r * 136 + c + 1] = f2bf(a1);
            As[r * 136 + c + 2] = f2bf(a2);
            As[r * 136 + c + 3] = f2bf(a3);
        }
    }
    __syncthreads();

    int w  = tid >> 6;
    int l  = tid & 63;
    int lr = l & 15, lk = l >> 4;

    f32x4 acc[15];
#pragma unroll
    for (int nt = 0; nt < 15; nt++) acc[nt] = (f32x4){0.f, 0.f, 0.f, 0.f};

#pragma unroll
    for (int kk = 0; kk < 4; kk++) {
        short8 a = *(const short8*)(&As[(w * 16 + lr) * 136 + kk * 32 + lk * 8]);
#pragma unroll
        for (int nt = 0; nt < 15; nt++) {
            short8 b = *(const short8*)(&Bs[(nt * 16 + lr) * 136 + kk * 32 + lk * 8]);
            acc[nt] = __builtin_amdgcn_mfma_f32_16x16x32_bf16(a, b, acc[nt], 0, 0, 0);
        }
    }

    int row0 = block_m + w * 16 + lk * 4;
#pragma unroll
    for (int nt = 0; nt < 8; nt++) {
        int col = nt * 16 + lr;
        float bb = bv[col];
#pragma unroll
        for (int r = 0; r < 4; r++)
            val[(size_t)(row0 + r) * CC + col] = f2bf(acc[nt][r] + bb);
    }
#pragma unroll
    for (int nt = 8; nt < 15; nt++) {
        int col = (nt - 8) * 16 + lr;        // 0..111
        float bb = (col < 108) ? bom[col] : 0.0f;
#pragma unroll
        for (int r = 0; r < 4; r++)
            omb[(size_t)(row0 + r) * OMP + col] = acc[nt][r] + bb;
    }
}

// ---------------------------------------------------------------------------
// Deformable sampling (bf16 value): 4 lanes per (nl,g) unit, 8 channels/lane
// (was 8 lanes x 4 ch). Halves om-load redundancy and per-unit weight VALU
// again; val gathers widen to dwordx4 (16B/lane, same 64B line per corner).
// Per-channel accumulation chains (corner order, k order) are bit-identical
// to the verified baseline.
// ---------------------------------------------------------------------------
__global__ __launch_bounds__(256) void sample_kernel(
    const unsigned short* __restrict__ val, const float* __restrict__ omb,
    unsigned int* __restrict__ sbuf)
{
    int tid   = threadIdx.x;
    int gid   = blockIdx.x * 256 + tid;
    int unit  = gid >> 2;                    // 65536 units
    int lane4 = gid & 3;
    int nl = unit >> 2;
    int g  = unit & 3;
    int n  = nl >> 12;
    int hw = nl & 4095;
    int h  = hw >> 6;
    int w  = hw & 63;

    const float* omp = omb + (size_t)nl * OMP + g * 27;
    const unsigned short* vb = val + (((size_t)n) << 19) + g * 32 + lane4 * 8;

    float acc0 = 0.0f, acc1 = 0.0f, acc2 = 0.0f, acc3 = 0.0f;
    float acc4 = 0.0f, acc5 = 0.0f, acc6 = 0.0f, acc7 = 0.0f;
#pragma unroll
    for (int k = 0; k < 9; k++) {
        float ox = omp[2 * k];
        float oy = omp[2 * k + 1];
        float mk = omp[18 + k];
        float ly = (float)(h + k / 3 - 1) + oy;
        float lx = (float)(w + k % 3 - 1) + ox;
        float y0f = floorf(ly), x0f = floorf(lx);
        float wy = ly - y0f, wx = lx - x0f;
        int y0 = (int)y0f, x0 = (int)x0f;

        float v0 = 0.0f, v1 = 0.0f, v2 = 0.0f, v3 = 0.0f;
        float v4 = 0.0f, v5 = 0.0f, v6 = 0.0f, v7 = 0.0f;
#pragma unroll
        for (int cy = 0; cy < 2; cy++) {
#pragma unroll
            for (int cx = 0; cx < 2; cx++) {
                int yi = y0 + cy, xi = x0 + cx;
                float wgt = (cy ? wy : 1.0f - wy) * (cx ? wx : 1.0f - wx);
                bool valid = (yi >= 0) && (yi < HH) && (xi >= 0) && (xi < WW);
                wgt = valid ? wgt : 0.0f;
                int yc = min(max(yi, 0), HH - 1);
                int xc = min(max(xi, 0), WW - 1);
                uint4 pv = *(const uint4*)(vb + (size_t)(yc * WW + xc) * CC);
                v0 += bf2f((unsigned short)(pv.x & 0xffff)) * wgt;
                v1 += bf2f((unsigned short)(pv.x >> 16)) * wgt;
                v2 += bf2f((unsigned short)(pv.y & 0xffff)) * wgt;
                v3 += bf2f((unsigned short)(pv.y >> 16)) * wgt;
                v4 += bf2f((unsigned short)(pv.z & 0xffff)) * wgt;
                v5 += bf2f((unsigned short)(pv.z >> 16)) * wgt;
                v6 += bf2f((unsigned short)(pv.w & 0xffff)) * wgt;
                v7 += bf2f((unsigned short)(pv.w >> 16)) * wgt;
            }
        }
        acc0 += mk * v0;
        acc1 += mk * v1;
        acc2 += mk * v2;
        acc3 += mk * v3;
        acc4 += mk * v4;
        acc5 += mk * v5;
        acc6 += mk * v6;
        acc7 += mk * v7;
    }
    uint4 packed;
    packed.x = (unsigned int)f2bf(acc0) | ((unsigned int)f2bf(acc1) << 16);
    packed.y = (unsigned int)f2bf(acc2) | ((unsigned int)f2bf(acc3) << 16);
    packed.z = (unsigned int)f2bf(acc4) | ((unsigned int)f2bf(acc5) << 16);
    packed.w = (unsigned int)f2bf(acc6) | ((unsigned int)f2bf(acc7) << 16);
    *(uint4*)(&sbuf[(size_t)nl * 64 + g * 16 + lane4 * 4]) = packed;
}

// ---------------------------------------------------------------------------
// Wo GEMM + fused BN-stats: ybuf = sbuf @ Wo ; stats[c] += sum, stats[128+c] += sumsq
// 2x2 wave grid, 64-row tile.
// ---------------------------------------------------------------------------
__global__ __launch_bounds__(256) void gemm_o_bn_kernel(
    const unsigned short* __restrict__ A, const unsigned short* __restrict__ Bt,
    float* __restrict__ ybuf, float* __restrict__ stats)
{
    __shared__ unsigned short As[64 * 136];
    __shared__ unsigned short Bs[128 * 136];
    __shared__ float lstat[256];

    int tid = threadIdx.x;
    int block_m = blockIdx.x * 64;
    lstat[tid] = 0.0f;

#pragma unroll
    for (int i = 0; i < 4; i++) {
        int id = tid + i * 256;
        int r = id >> 4, kc = id & 15;
        float4 v = *(const float4*)(A + (size_t)(block_m + r) * CC + kc * 8);
        *(float4*)(&As[r * 136 + kc * 8]) = v;
    }
#pragma unroll
    for (int i = 0; i < 8; i++) {
        int id = tid + i * 256;
        int r = id >> 4, kc = id & 15;
        float4 v = *(const float4*)(Bt + (size_t)r * CC + kc * 8);
        *(float4*)(&Bs[r * 136 + kc * 8]) = v;
    }
    __syncthreads();

    int w  = tid >> 6;
    int l  = tid & 63;
    int wm = w & 1, wn = w >> 1;
    int lr = l & 15, lk = l >> 4;

    f32x4 acc[2][4];
#pragma unroll
    for (int mt = 0; mt < 2; mt++)
#pragma unroll
        for (int nt = 0; nt < 4; nt++) acc[mt][nt] = (f32x4){0.f, 0.f, 0.f, 0.f};

#pragma unroll
    for (int kk = 0; kk < 4; kk++) {
        short8 a[2], b[4];
#pragma unroll
        for (int mt = 0; mt < 2; mt++)
            a[mt] = *(const short8*)(&As[(wm * 32 + mt * 16 + lr) * 136 + kk * 32 + lk * 8]);
#pragma unroll
        for (int nt = 0; nt < 4; nt++)
            b[nt] = *(const short8*)(&Bs[(wn * 64 + nt * 16 + lr) * 136 + kk * 32 + lk * 8]);
#pragma unroll
        for (int mt = 0; mt < 2; mt++)
#pragma unroll
            for (int nt = 0; nt < 4; nt++)
                acc[mt][nt] = __builtin_amdgcn_mfma_f32_16x16x32_bf16(
                    a[mt], b[nt], acc[mt][nt], 0, 0, 0);
    }

    // write + per-lane stats
#pragma unroll
    for (int nt = 0; nt < 4; nt++) {
        int col = wn * 64 + nt * 16 + lr;
        float s = 0.0f, sq = 0.0f;
#pragma unroll
        for (int mt = 0; mt < 2; mt++) {
            int row0 = block_m + wm * 32 + mt * 16 + lk * 4;
#pragma unroll
            for (int r = 0; r < 4; r++) {
                float v = acc[mt][nt][r];
                ybuf[(size_t)(row0 + r) * CC + col] = v;
                s += v;
                sq += v * v;
            }
        }
        atomicAdd(&lstat[col], s);
        atomicAdd(&lstat[128 + col], sq);
    }
    __syncthreads();
    if (tid < 128) {
        atomicAdd(&stats[tid], lstat[tid]);
        atomicAdd(&stats[128 + tid], lstat[128 + tid]);
    }
}

// ---------------------------------------------------------------------------
// Final GEMM: A = bn(ybuf) + x_residual(NCHW), B = Wc; out NCHW fp32.
// ---------------------------------------------------------------------------
__global__ __launch_bounds__(256) void gemm_final_kernel(
    const float* __restrict__ ybuf, const float* __restrict__ x,
    const unsigned short* __restrict__ Bt, const float* __restrict__ stats,
    const float* __restrict__ gamma, const float* __restrict__ beta,
    float* __restrict__ out)
{
    __shared__ unsigned short As[64 * 136];
    __shared__ unsigned short Bs[128 * 136];
    __shared__ float Xs[64 * 132];
    __shared__ float bnsc[128], bnsh[128];

    int tid = threadIdx.x;
    int block_m = blockIdx.x * 64;
    int n   = block_m >> 12;
    int hw0 = block_m & 4095;

    if (tid < 128) {
        const float inv = 1.0f / 16384.0f;
        float mean = stats[tid] * inv;
        float var  = stats[128 + tid] * inv - mean * mean;
        float sc   = rsqrtf(var + 1e-5f) * gamma[tid];
        bnsc[tid] = sc;
        bnsh[tid] = beta[tid] - mean * sc;
    }

    // stage x residual (NCHW -> LDS transpose, fp32)
#pragma unroll
    for (int i = 0; i < 8; i++) {
        int id = tid + i * 256;
        int c  = id >> 4, j4 = id & 15;
        float4 v = *(const float4*)(x + (((size_t)(n * CC + c)) << 12) + hw0 + j4 * 4);
        Xs[(j4 * 4 + 0) * 132 + c] = v.x;
        Xs[(j4 * 4 + 1) * 132 + c] = v.y;
        Xs[(j4 * 4 + 2) * 132 + c] = v.z;
        Xs[(j4 * 4 + 3) * 132 + c] = v.w;
    }
    // stage B
#pragma unroll
    for (int i = 0; i < 8; i++) {
        int id = tid + i * 256;
        int r = id >> 4, kc = id & 15;
        float4 v = *(const float4*)(Bt + (size_t)r * CC + kc * 8);
        *(float4*)(&Bs[r * 136 + kc * 8]) = v;
    }
    __syncthreads();

    // stage A = bn(ybuf) + Xs
#pragma unroll
    for (int i = 0; i < 8; i++) {
        int id = tid + i * 256;
        int r  = id >> 5, c4 = id & 31;
        float4 v = *(const float4*)(ybuf + (size_t)(block_m + r) * CC + c4 * 4);
        int c = c4 * 4;
        float a0 = v.x * bnsc[c + 0] + bnsh[c + 0] + Xs[r * 132 + c + 0];
        float a1 = v.y * bnsc[c + 1] + bnsh[c + 1] + Xs[r * 132 + c + 1];
        float a2 = v.z * bnsc[c + 2] + bnsh[c + 2] + Xs[r * 132 + c + 2];
        float a3 = v.w * bnsc[c + 3] + bnsh[c + 3] + Xs[r * 132 + c + 3];
        As[r * 136 + c + 0] = f2bf(a0);
        As[r * 136 + c + 1] = f2bf(a1);
        As[r * 136 + c + 2] = f2bf(a2);
        As[r * 136 + c + 3] = f2bf(a3);
    }
    __syncthreads();

    int w  = tid >> 6;
    int l  = tid & 63;
    int wm = w & 1, wn = w >> 1;
    int lr = l & 15, lk = l >> 4;

    f32x4 acc[2][4];
#pragma unroll
    for (int mt = 0; mt < 2; mt++)
#pragma unroll
        for (int nt = 0; nt < 4; nt++) acc[mt][nt] = (f32x4){0.f, 0.f, 0.f, 0.f};

#pragma unroll
    for (int kk = 0; kk < 4; kk++) {
        short8 a[2], b[4];
#pragma unroll
        for (int mt = 0; mt < 2; mt++)
            a[mt] = *(const short8*)(&As[(wm * 32 + mt * 16 + lr) * 136 + kk * 32 + lk * 8]);
#pragma unroll
        for (int nt = 0; nt < 4; nt++)
            b[nt] = *(const short8*)(&Bs[(wn * 64 + nt * 16 + lr) * 136 + kk * 32 + lk * 8]);
#pragma unroll
        for (int mt = 0; mt < 2; mt++)
#pragma unroll
            for (int nt = 0; nt < 4; nt++)
                acc[mt][nt] = __builtin_amdgcn_mfma_f32_16x16x32_bf16(
                    a[mt], b[nt], acc[mt][nt], 0, 0, 0);
    }

    // NCHW scatter via LDS transpose (reuse Bs as float[128][68])
    __syncthreads();
    float* T = (float*)Bs;
#pragma unroll
    for (int mt = 0; mt < 2; mt++) {
        int rloc = wm * 32 + mt * 16 + lk * 4;
#pragma unroll
        for (int nt = 0; nt < 4; nt++) {
            int col = wn * 64 + nt * 16 + lr;
#pragma unroll
            for (int r = 0; r < 4; r++)
                T[col * 68 + rloc + r] = acc[mt][nt][r];
        }
    }
    __syncthreads();
    int o = tid >> 1, half = tid & 1;
    float* op = out + (((size_t)(n * CC + o)) << 12) + hw0 + half * 32;
#pragma unroll
    for (int i = 0; i < 8; i++) {
        float4 v = *(const float4*)(&T[o * 68 + half * 32 + i * 4]);
        *(float4*)(op + i * 4) = v;
    }
}

// ---------------------------------------------------------------------------
extern "C" void kernel_launch(void* const* d_in, const int* in_sizes, int n_in,
                              void* d_out, int out_size, void* d_ws, size_t ws_size,
                              hipStream_t stream)
{
    const float* x     = (const float*)d_in[0];
    const float* Wv    = (const float*)d_in[1];
    const float* bv    = (const float*)d_in[2];
    const float* Wom   = (const float*)d_in[3];
    const float* bom   = (const float*)d_in[4];
    const float* Wo    = (const float*)d_in[5];
    const float* gamma = (const float*)d_in[6];
    const float* beta  = (const float*)d_in[7];
    const float* Wc    = (const float*)d_in[8];
    float* out = (float*)d_out;

    char* ws = (char*)d_ws;
    unsigned short* val   = (unsigned short*)ws;   ws += (size_t)NL * CC * 2;    // 4 MB
    float*          omb   = (float*)ws;            ws += (size_t)NL * OMP * 4;   // 7.34 MB
    unsigned int*   sbuf  = (unsigned int*)ws;     ws += (size_t)NL * CC * 2;    // 4 MB
    float*          ybuf  = (float*)ws;            ws += (size_t)NL * CC * 4;    // 8 MB
    unsigned short* Wcomb = (unsigned short*)ws;   ws += 240 * 128 * 2;
    unsigned short* WoT   = (unsigned short*)ws;   ws += 128 * 128 * 2;
    unsigned short* Wcb   = (unsigned short*)ws;   ws += 128 * 128 * 2;
    float*          stats = (float*)ws;            ws += 2048;

    dim3 b256(256);

    prep_kernel<<<248, b256, 0, stream>>>(Wv, Wom, Wo, Wc, Wcomb, WoT, Wcb, stats);

    // ---- DCN block 1 ----
    gemm_vom_kernel<0><<<256, b256, 0, stream>>>(x, Wcomb, bv, bom,
                                                 nullptr, nullptr, nullptr, val, omb);
    sample_kernel<<<1024, b256, 0, stream>>>(val, omb, sbuf);
    gemm_o_bn_kernel<<<256, b256, 0, stream>>>((const unsigned short*)sbuf, WoT, ybuf, stats);

    // ---- DCN block 2 (bn+relu fused into A-staging) ----
    gemm_vom_kernel<1><<<256, b256, 0, stream>>>(ybuf, Wcomb, bv, bom,
                                                 stats, gamma, beta, val, omb);
    sample_kernel<<<1024, b256, 0, stream>>>(val, omb, sbuf);
    gemm_o_bn_kernel<<<256, b256, 0, stream>>>((const unsigned short*)sbuf, WoT, ybuf, stats + 256);

    // ---- final: bn2 + residual + 1x1 conv, NCHW out ----
    gemm_final_kernel<<<256, b256, 0, stream>>>(ybuf, x, Wcb, stats + 256, gamma, beta, out);
}

// Round 7
// 148.025 us; speedup vs baseline: 9.2139x; 1.0059x over previous
//
#include <hip/hip_runtime.h>
#include <math.h>

// Problem constants
#define CC   128         // channels
#define NL   16384       // N * H * W = 4*64*64
#define LHW  4096        // H*W
#define OMP  112         // padded om row stride: 4 groups x (27+1 pad) floats
#define HH   64
#define WW   64

typedef __attribute__((ext_vector_type(8))) short short8;
typedef __attribute__((ext_vector_type(4))) float f32x4;

__device__ __forceinline__ unsigned short f2bf(float f) {
    union { float f; unsigned u; } v; v.f = f;
    unsigned r = v.u + 0x7fff + ((v.u >> 16) & 1);   // RNE
    return (unsigned short)(r >> 16);
}
__device__ __forceinline__ float bf2f(unsigned short u) {
    union { unsigned u; float f; } v; v.u = ((unsigned)u) << 16;
    return v.f;
}

// ---------------------------------------------------------------------------
// Weight prep + stats zero.
// Wcomb[240][128] bf16: rows 0..127 = Wv^T, rows 128..239 = Wom^T (pad 108->112)
// WoT[128][128] = Wo^T ; Wcb[128][128] = Wc (already Bt layout: [o][c]).
// ---------------------------------------------------------------------------
__global__ __launch_bounds__(256) void prep_kernel(
    const float* __restrict__ Wv, const float* __restrict__ Wom,
    const float* __restrict__ Wo, const float* __restrict__ Wc,
    unsigned short* __restrict__ Wcomb, unsigned short* __restrict__ WoT,
    unsigned short* __restrict__ Wcb, float* __restrict__ stats)
{
    int tid = threadIdx.x;
    if (blockIdx.x == 0) {               // zero 512 stats floats
        stats[tid] = 0.0f;
        stats[256 + tid] = 0.0f;
    }
    int i = blockIdx.x * 256 + tid;      // 63488 total
    if (i < 16384) {
        int n = i >> 7, k = i & 127;
        Wcomb[i] = f2bf(Wv[k * CC + n]);
    } else if (i < 30720) {
        int j = i - 16384; int n = j >> 7, k = j & 127;   // n in 0..111
        Wcomb[16384 + j] = (n < 108) ? f2bf(Wom[k * 108 + n]) : (unsigned short)0;
    } else if (i < 47104) {
        int j = i - 30720; int n = j >> 7, k = j & 127;
        WoT[j] = f2bf(Wo[k * CC + n]);
    } else if (i < 63488) {
        int j = i - 47104;
        Wcb[j] = f2bf(Wc[j]);
    }
}

// ---------------------------------------------------------------------------
// Fused value+om GEMM: [M=16384 x N=240 x K=128].
// IN_MODE 0: A = x in NCHW (transpose in LDS staging).
// IN_MODE 1: A = bn_relu(ybuf) (NHWC), stats/gamma/beta applied in staging.
// Outputs:
//   val bf16 in g-major layout [n][g][hw][32] (+bv)  -- sample-gather friendly
//   omb fp32 in layout [nl][4][28] (+bom, e<27)      -- 16B-aligned g-slices
// 4 waves; wave w computes rows w*16..w*16+15 x all 240 cols (15 frags).
// MFMA chains identical to the verified baseline; only store addressing moved.
// ---------------------------------------------------------------------------
template<int IN_MODE>
__global__ __launch_bounds__(256) void gemm_vom_kernel(
    const float* __restrict__ Ain, const unsigned short* __restrict__ Wcomb,
    const float* __restrict__ bv, const float* __restrict__ bom,
    const float* __restrict__ stats, const float* __restrict__ gamma,
    const float* __restrict__ beta,
    unsigned short* __restrict__ val, float* __restrict__ omb)
{
    __shared__ unsigned short As[64 * 136];
    __shared__ unsigned short Bs[240 * 136];
    __shared__ float bnsc[128], bnsh[128];

    int tid = threadIdx.x;
    int block_m = blockIdx.x * 64;

    if (IN_MODE == 1 && tid < 128) {
        const float inv = 1.0f / 16384.0f;
        float mean = stats[tid] * inv;
        float var  = stats[128 + tid] * inv - mean * mean;
        float sc   = rsqrtf(var + 1e-5f) * gamma[tid];
        bnsc[tid] = sc;
        bnsh[tid] = beta[tid] - mean * sc;
    }

    // stage B: 240 rows x 128 bf16 = 3840 chunks of 8  (15 x 256, exact)
#pragma unroll
    for (int i = 0; i < 15; i++) {
        int id = tid + i * 256;
        int r = id >> 4, kc = id & 15;
        float4 v = *(const float4*)(Wcomb + (size_t)r * CC + kc * 8);
        *(float4*)(&Bs[r * 136 + kc * 8]) = v;
    }

    if (IN_MODE == 0) {
        // A from x NCHW: 128 channels x 16 float4 along hw
        int n   = block_m >> 12;
        int hw0 = block_m & 4095;
#pragma unroll
        for (int i = 0; i < 8; i++) {
            int id = tid + i * 256;          // 0..2047
            int c  = id >> 4, j4 = id & 15;
            float4 v = *(const float4*)(Ain + (((size_t)(n * CC + c)) << 12) + hw0 + j4 * 4);
            As[(j4 * 4 + 0) * 136 + c] = f2bf(v.x);
            As[(j4 * 4 + 1) * 136 + c] = f2bf(v.y);
            As[(j4 * 4 + 2) * 136 + c] = f2bf(v.z);
            As[(j4 * 4 + 3) * 136 + c] = f2bf(v.w);
        }
    } else {
        __syncthreads();                     // bnsc/bnsh ready
#pragma unroll
        for (int i = 0; i < 8; i++) {
            int id = tid + i * 256;          // 0..2047
            int r  = id >> 5, c4 = id & 31;
            float4 v = *(const float4*)(Ain + (size_t)(block_m + r) * CC + c4 * 4);
            int c = c4 * 4;
            float a0 = fmaxf(v.x * bnsc[c + 0] + bnsh[c + 0], 0.0f);
            float a1 = fmaxf(v.y * bnsc[c + 1] + bnsh[c + 1], 0.0f);
            float a2 = fmaxf(v.z * bnsc[c + 2] + bnsh[c + 2], 0.0f);
            float a3 = fmaxf(v.w * bnsc[c + 3] + bnsh[c + 3], 0.0f);
            As[r * 136 + c + 0] = f2bf(a0);
            As[r * 136 + c + 1] = f2bf(a1);
            As[r * 136 + c + 2] = f2bf(a2);
            As[r * 136 + c + 3] = f2bf(a3);
        }
    }
    __syncthreads();

    int w  = tid >> 6;
    int l  = tid & 63;
    int lr = l & 15, lk = l >> 4;

    f32x4 acc[15];
#pragma unroll
    for (int nt = 0; nt < 15; nt++) acc[nt] = (f32x4){0.f, 0.f, 0.f, 0.f};

#pragma unroll
    for (int kk = 0; kk < 4; kk++) {
        short8 a = *(const short8*)(&As[(w * 16 + lr) * 136 + kk * 32 + lk * 8]);
#pragma unroll
        for (int nt = 0; nt < 15; nt++) {
            short8 b = *(const short8*)(&Bs[(nt * 16 + lr) * 136 + kk * 32 + lk * 8]);
            acc[nt] = __builtin_amdgcn_mfma_f32_16x16x32_bf16(a, b, acc[nt], 0, 0, 0);
        }
    }

    int row0  = block_m + w * 16 + lk * 4;
    int nimg  = block_m >> 12;               // constant per block (4096 % 64 == 0)
    int hwrow = row0 & 4095;
#pragma unroll
    for (int nt = 0; nt < 8; nt++) {
        int col = nt * 16 + lr;
        float bb = bv[col];
        int gg = col >> 5, ch = col & 31;
        unsigned short* vp = val + (((size_t)(nimg * 4 + gg)) << 17) + (size_t)hwrow * 32 + ch;
#pragma unroll
        for (int r = 0; r < 4; r++)
            vp[r * 32] = f2bf(acc[nt][r] + bb);
    }
#pragma unroll
    for (int nt = 8; nt < 15; nt++) {
        int col = (nt - 8) * 16 + lr;        // 0..111
        if (col < 108) {
            int gg = col / 27, e = col - gg * 27;
            float bb = bom[col];
#pragma unroll
            for (int r = 0; r < 4; r++)
                omb[(size_t)(row0 + r) * OMP + gg * 28 + e] = acc[nt][r] + bb;
        }
    }
}

// ---------------------------------------------------------------------------
// Deformable sampling: 4 lanes x 8 ch per (nl,g) unit.
// val in g-major layout: pixel g-slice = 64B contiguous; corner pair
// (x0,x0+1) = one 128B line. om loaded as 7 x float4 (16B-aligned 28-slice).
// Per-channel accumulation chains bit-identical to the verified baseline.
// ---------------------------------------------------------------------------
__global__ __launch_bounds__(256) void sample_kernel(
    const unsigned short* __restrict__ val, const float* __restrict__ omb,
    unsigned int* __restrict__ sbuf)
{
    int tid   = threadIdx.x;
    int gid   = blockIdx.x * 256 + tid;
    int unit  = gid >> 2;                    // 65536 units
    int lane4 = gid & 3;
    int nl = unit >> 2;
    int g  = unit & 3;
    int n  = nl >> 12;
    int hw = nl & 4095;
    int h  = hw >> 6;
    int w  = hw & 63;

    const float* omp = omb + (size_t)nl * OMP + g * 28;   // 16B aligned
    f32x4 o4[7];
#pragma unroll
    for (int i = 0; i < 7; i++) o4[i] = *(const f32x4*)(omp + i * 4);

    const unsigned short* vb = val + (((size_t)(n * 4 + g)) << 17) + lane4 * 8;

    float acc0 = 0.0f, acc1 = 0.0f, acc2 = 0.0f, acc3 = 0.0f;
    float acc4 = 0.0f, acc5 = 0.0f, acc6 = 0.0f, acc7 = 0.0f;
#pragma unroll
    for (int k = 0; k < 9; k++) {
        float ox = o4[(2 * k) >> 2][(2 * k) & 3];
        float oy = o4[(2 * k + 1) >> 2][(2 * k + 1) & 3];
        float mk = o4[(18 + k) >> 2][(18 + k) & 3];
        float ly = (float)(h + k / 3 - 1) + oy;
        float lx = (float)(w + k % 3 - 1) + ox;
        float y0f = floorf(ly), x0f = floorf(lx);
        float wy = ly - y0f, wx = lx - x0f;
        int y0 = (int)y0f, x0 = (int)x0f;

        float v0 = 0.0f, v1 = 0.0f, v2 = 0.0f, v3 = 0.0f;
        float v4 = 0.0f, v5 = 0.0f, v6 = 0.0f, v7 = 0.0f;
#pragma unroll
        for (int cy = 0; cy < 2; cy++) {
#pragma unroll
            for (int cx = 0; cx < 2; cx++) {
                int yi = y0 + cy, xi = x0 + cx;
                float wgt = (cy ? wy : 1.0f - wy) * (cx ? wx : 1.0f - wx);
                bool valid = (yi >= 0) && (yi < HH) && (xi >= 0) && (xi < WW);
                wgt = valid ? wgt : 0.0f;
                int yc = min(max(yi, 0), HH - 1);
                int xc = min(max(xi, 0), WW - 1);
                uint4 pv = *(const uint4*)(vb + (size_t)(yc * WW + xc) * 32);
                v0 += bf2f((unsigned short)(pv.x & 0xffff)) * wgt;
                v1 += bf2f((unsigned short)(pv.x >> 16)) * wgt;
                v2 += bf2f((unsigned short)(pv.y & 0xffff)) * wgt;
                v3 += bf2f((unsigned short)(pv.y >> 16)) * wgt;
                v4 += bf2f((unsigned short)(pv.z & 0xffff)) * wgt;
                v5 += bf2f((unsigned short)(pv.z >> 16)) * wgt;
                v6 += bf2f((unsigned short)(pv.w & 0xffff)) * wgt;
                v7 += bf2f((unsigned short)(pv.w >> 16)) * wgt;
            }
        }
        acc0 += mk * v0;
        acc1 += mk * v1;
        acc2 += mk * v2;
        acc3 += mk * v3;
        acc4 += mk * v4;
        acc5 += mk * v5;
        acc6 += mk * v6;
        acc7 += mk * v7;
    }
    uint4 packed;
    packed.x = (unsigned int)f2bf(acc0) | ((unsigned int)f2bf(acc1) << 16);
    packed.y = (unsigned int)f2bf(acc2) | ((unsigned int)f2bf(acc3) << 16);
    packed.z = (unsigned int)f2bf(acc4) | ((unsigned int)f2bf(acc5) << 16);
    packed.w = (unsigned int)f2bf(acc6) | ((unsigned int)f2bf(acc7) << 16);
    *(uint4*)(&sbuf[(size_t)nl * 64 + g * 16 + lane4 * 4]) = packed;
}

// ---------------------------------------------------------------------------
// Wo GEMM + fused BN-stats: ybuf = sbuf @ Wo ; stats[c] += sum, stats[128+c] += sumsq
// 2x2 wave grid, 64-row tile.
// ---------------------------------------------------------------------------
__global__ __launch_bounds__(256) void gemm_o_bn_kernel(
    const unsigned short* __restrict__ A, const unsigned short* __restrict__ Bt,
    float* __restrict__ ybuf, float* __restrict__ stats)
{
    __shared__ unsigned short As[64 * 136];
    __shared__ unsigned short Bs[128 * 136];
    __shared__ float lstat[256];

    int tid = threadIdx.x;
    int block_m = blockIdx.x * 64;
    lstat[tid] = 0.0f;

#pragma unroll
    for (int i = 0; i < 4; i++) {
        int id = tid + i * 256;
        int r = id >> 4, kc = id & 15;
        float4 v = *(const float4*)(A + (size_t)(block_m + r) * CC + kc * 8);
        *(float4*)(&As[r * 136 + kc * 8]) = v;
    }
#pragma unroll
    for (int i = 0; i < 8; i++) {
        int id = tid + i * 256;
        int r = id >> 4, kc = id & 15;
        float4 v = *(const float4*)(Bt + (size_t)r * CC + kc * 8);
        *(float4*)(&Bs[r * 136 + kc * 8]) = v;
    }
    __syncthreads();

    int w  = tid >> 6;
    int l  = tid & 63;
    int wm = w & 1, wn = w >> 1;
    int lr = l & 15, lk = l >> 4;

    f32x4 acc[2][4];
#pragma unroll
    for (int mt = 0; mt < 2; mt++)
#pragma unroll
        for (int nt = 0; nt < 4; nt++) acc[mt][nt] = (f32x4){0.f, 0.f, 0.f, 0.f};

#pragma unroll
    for (int kk = 0; kk < 4; kk++) {
        short8 a[2], b[4];
#pragma unroll
        for (int mt = 0; mt < 2; mt++)
            a[mt] = *(const short8*)(&As[(wm * 32 + mt * 16 + lr) * 136 + kk * 32 + lk * 8]);
#pragma unroll
        for (int nt = 0; nt < 4; nt++)
            b[nt] = *(const short8*)(&Bs[(wn * 64 + nt * 16 + lr) * 136 + kk * 32 + lk * 8]);
#pragma unroll
        for (int mt = 0; mt < 2; mt++)
#pragma unroll
            for (int nt = 0; nt < 4; nt++)
                acc[mt][nt] = __builtin_amdgcn_mfma_f32_16x16x32_bf16(
                    a[mt], b[nt], acc[mt][nt], 0, 0, 0);
    }

    // write + per-lane stats
#pragma unroll
    for (int nt = 0; nt < 4; nt++) {
        int col = wn * 64 + nt * 16 + lr;
        float s = 0.0f, sq = 0.0f;
#pragma unroll
        for (int mt = 0; mt < 2; mt++) {
            int row0 = block_m + wm * 32 + mt * 16 + lk * 4;
#pragma unroll
            for (int r = 0; r < 4; r++) {
                float v = acc[mt][nt][r];
                ybuf[(size_t)(row0 + r) * CC + col] = v;
                s += v;
                sq += v * v;
            }
        }
        atomicAdd(&lstat[col], s);
        atomicAdd(&lstat[128 + col], sq);
    }
    __syncthreads();
    if (tid < 128) {
        atomicAdd(&stats[tid], lstat[tid]);
        atomicAdd(&stats[128 + tid], lstat[128 + tid]);
    }
}

// ---------------------------------------------------------------------------
// Final GEMM: A = bn(ybuf) + x_residual(NCHW), B = Wc; out NCHW fp32.
// ---------------------------------------------------------------------------
__global__ __launch_bounds__(256) void gemm_final_kernel(
    const float* __restrict__ ybuf, const float* __restrict__ x,
    const unsigned short* __restrict__ Bt, const float* __restrict__ stats,
    const float* __restrict__ gamma, const float* __restrict__ beta,
    float* __restrict__ out)
{
    __shared__ unsigned short As[64 * 136];
    __shared__ unsigned short Bs[128 * 136];
    __shared__ float Xs[64 * 132];
    __shared__ float bnsc[128], bnsh[128];

    int tid = threadIdx.x;
    int block_m = blockIdx.x * 64;
    int n   = block_m >> 12;
    int hw0 = block_m & 4095;

    if (tid < 128) {
        const float inv = 1.0f / 16384.0f;
        float mean = stats[tid] * inv;
        float var  = stats[128 + tid] * inv - mean * mean;
        float sc   = rsqrtf(var + 1e-5f) * gamma[tid];
        bnsc[tid] = sc;
        bnsh[tid] = beta[tid] - mean * sc;
    }

    // stage x residual (NCHW -> LDS transpose, fp32)
#pragma unroll
    for (int i = 0; i < 8; i++) {
        int id = tid + i * 256;
        int c  = id >> 4, j4 = id & 15;
        float4 v = *(const float4*)(x + (((size_t)(n * CC + c)) << 12) + hw0 + j4 * 4);
        Xs[(j4 * 4 + 0) * 132 + c] = v.x;
        Xs[(j4 * 4 + 1) * 132 + c] = v.y;
        Xs[(j4 * 4 + 2) * 132 + c] = v.z;
        Xs[(j4 * 4 + 3) * 132 + c] = v.w;
    }
    // stage B
#pragma unroll
    for (int i = 0; i < 8; i++) {
        int id = tid + i * 256;
        int r = id >> 4, kc = id & 15;
        float4 v = *(const float4*)(Bt + (size_t)r * CC + kc * 8);
        *(float4*)(&Bs[r * 136 + kc * 8]) = v;
    }
    __syncthreads();

    // stage A = bn(ybuf) + Xs
#pragma unroll
    for (int i = 0; i < 8; i++) {
        int id = tid + i * 256;
        int r  = id >> 5, c4 = id & 31;
        float4 v = *(const float4*)(ybuf + (size_t)(block_m + r) * CC + c4 * 4);
        int c = c4 * 4;
        float a0 = v.x * bnsc[c + 0] + bnsh[c + 0] + Xs[r * 132 + c + 0];
        float a1 = v.y * bnsc[c + 1] + bnsh[c + 1] + Xs[r * 132 + c + 1];
        float a2 = v.z * bnsc[c + 2] + bnsh[c + 2] + Xs[r * 132 + c + 2];
        float a3 = v.w * bnsc[c + 3] + bnsh[c + 3] + Xs[r * 132 + c + 3];
        As[r * 136 + c + 0] = f2bf(a0);
        As[r * 136 + c + 1] = f2bf(a1);
        As[r * 136 + c + 2] = f2bf(a2);
        As[r * 136 + c + 3] = f2bf(a3);
    }
    __syncthreads();

    int w  = tid >> 6;
    int l  = tid & 63;
    int wm = w & 1, wn = w >> 1;
    int lr = l & 15, lk = l >> 4;

    f32x4 acc[2][4];
#pragma unroll
    for (int mt = 0; mt < 2; mt++)
#pragma unroll
        for (int nt = 0; nt < 4; nt++) acc[mt][nt] = (f32x4){0.f, 0.f, 0.f, 0.f};

#pragma unroll
    for (int kk = 0; kk < 4; kk++) {
        short8 a[2], b[4];
#pragma unroll
        for (int mt = 0; mt < 2; mt++)
            a[mt] = *(const short8*)(&As[(wm * 32 + mt * 16 + lr) * 136 + kk * 32 + lk * 8]);
#pragma unroll
        for (int nt = 0; nt < 4; nt++)
            b[nt] = *(const short8*)(&Bs[(wn * 64 + nt * 16 + lr) * 136 + kk * 32 + lk * 8]);
#pragma unroll
        for (int mt = 0; mt < 2; mt++)
#pragma unroll
            for (int nt = 0; nt < 4; nt++)
                acc[mt][nt] = __builtin_amdgcn_mfma_f32_16x16x32_bf16(
                    a[mt], b[nt], acc[mt][nt], 0, 0, 0);
    }

    // NCHW scatter via LDS transpose (reuse Bs as float[128][68])
    __syncthreads();
    float* T = (float*)Bs;
#pragma unroll
    for (int mt = 0; mt < 2; mt++) {
        int rloc = wm * 32 + mt * 16 + lk * 4;
#pragma unroll
        for (int nt = 0; nt < 4; nt++) {
            int col = wn * 64 + nt * 16 + lr;
#pragma unroll
            for (int r = 0; r < 4; r++)
                T[col * 68 + rloc + r] = acc[mt][nt][r];
        }
    }
    __syncthreads();
    int o = tid >> 1, half = tid & 1;
    float* op = out + (((size_t)(n * CC + o)) << 12) + hw0 + half * 32;
#pragma unroll
    for (int i = 0; i < 8; i++) {
        float4 v = *(const float4*)(&T[o * 68 + half * 32 + i * 4]);
        *(float4*)(op + i * 4) = v;
    }
}

// ---------------------------------------------------------------------------
extern "C" void kernel_launch(void* const* d_in, const int* in_sizes, int n_in,
                              void* d_out, int out_size, void* d_ws, size_t ws_size,
                              hipStream_t stream)
{
    const float* x     = (const float*)d_in[0];
    const float* Wv    = (const float*)d_in[1];
    const float* bv    = (const float*)d_in[2];
    const float* Wom   = (const float*)d_in[3];
    const float* bom   = (const float*)d_in[4];
    const float* Wo    = (const float*)d_in[5];
    const float* gamma = (const float*)d_in[6];
    const float* beta  = (const float*)d_in[7];
    const float* Wc    = (const float*)d_in[8];
    float* out = (float*)d_out;

    char* ws = (char*)d_ws;
    unsigned short* val   = (unsigned short*)ws;   ws += (size_t)NL * CC * 2;    // 4 MB
    float*          omb   = (float*)ws;            ws += (size_t)NL * OMP * 4;   // 7.34 MB
    unsigned int*   sbuf  = (unsigned int*)ws;     ws += (size_t)NL * CC * 2;    // 4 MB
    float*          ybuf  = (float*)ws;            ws += (size_t)NL * CC * 4;    // 8 MB
    unsigned short* Wcomb = (unsigned short*)ws;   ws += 240 * 128 * 2;
    unsigned short* WoT   = (unsigned short*)ws;   ws += 128 * 128 * 2;
    unsigned short* Wcb   = (unsigned short*)ws;   ws += 128 * 128 * 2;
    float*          stats = (float*)ws;            ws += 2048;

    dim3 b256(256);

    prep_kernel<<<248, b256, 0, stream>>>(Wv, Wom, Wo, Wc, Wcomb, WoT, Wcb, stats);

    // ---- DCN block 1 ----
    gemm_vom_kernel<0><<<256, b256, 0, stream>>>(x, Wcomb, bv, bom,
                                                 nullptr, nullptr, nullptr, val, omb);
    sample_kernel<<<1024, b256, 0, stream>>>(val, omb, sbuf);
    gemm_o_bn_kernel<<<256, b256, 0, stream>>>((const unsigned short*)sbuf, WoT, ybuf, stats);

    // ---- DCN block 2 (bn+relu fused into A-staging) ----
    gemm_vom_kernel<1><<<256, b256, 0, stream>>>(ybuf, Wcomb, bv, bom,
                                                 stats, gamma, beta, val, omb);
    sample_kernel<<<1024, b256, 0, stream>>>(val, omb, sbuf);
    gemm_o_bn_kernel<<<256, b256, 0, stream>>>((const unsigned short*)sbuf, WoT, ybuf, stats + 256);

    // ---- final: bn2 + residual + 1x1 conv, NCHW out ----
    gemm_final_kernel<<<256, b256, 0, stream>>>(ybuf, x, Wcb, stats + 256, gamma, beta, out);
}